// Round 4
// baseline (601.933 us; speedup 1.0000x reference)
//
#include <hip/hip_runtime.h>
#include <hip/hip_bf16.h>
#include <hip/hip_fp16.h>

#define N_NODES 100000
#define N_EDGES 20000
#define NNZ     1600000
#define D       128
#define STAR    64
#define NEG_SLOPE 0.2f

// edge counting-sort partition
#define NBLK_E  200         // chunks
#define CHUNK_E 8000        // NNZ / NBLK_E
#define BINS_E  10000       // bins per LDS pass (40 KB int), 2 passes

// node counting-sort partition (LDS atomics replace memory-side atomics)
#define NBLK_N  40          // chunks
#define CHUNK_N 40000       // NNZ / NBLK_N  (ranks < 65536 -> ushort ok)
#define BINS_N  10000       // bins per LDS pass, 10 passes
#define NPASS_N 10

// multi-block scan: 256 threads x 16 elements
#define SCC 16
#define SC_PER_BLOCK (256 * SCC)   // 4096
#define SC_NBLK(n) (((n) + SC_PER_BLOCK - 1) / SC_PER_BLOCK)

typedef _Float16 half8 __attribute__((ext_vector_type(8)));
typedef float    floatx4 __attribute__((ext_vector_type(4)));

// pack 8 fp32 (two float4) -> half8 fragment
__device__ __forceinline__ half8 cvt8(float4 f0, float4 f1)
{
    half8 h;
    h[0] = (_Float16)f0.x; h[1] = (_Float16)f0.y;
    h[2] = (_Float16)f0.z; h[3] = (_Float16)f0.w;
    h[4] = (_Float16)f1.x; h[5] = (_Float16)f1.y;
    h[6] = (_Float16)f1.z; h[7] = (_Float16)f1.w;
    return h;
}

// ---------------------------------------------------------------------------
// K0: one-time fp32 -> fp16 weight conversion.
// ---------------------------------------------------------------------------
__global__ __launch_bounds__(256) void k_cvt_w(
    const float* __restrict__ Wx, const float* __restrict__ Wv,
    const float* __restrict__ Wt,
    __half* __restrict__ Wf16, __half* __restrict__ Wtf16)
{
    int i = (blockIdx.x * 256 + threadIdx.x) * 4;
    const float* src;
    __half* dst;
    if (i < 16384)            { src = Wx + i;         dst = Wf16 + i; }
    else if (i < 32768)       { src = Wv + (i-16384); dst = Wf16 + i; }
    else if (i < 32768+24576) { src = Wt + (i-32768); dst = Wtf16 + (i-32768); }
    else return;
    float4 f = *(const float4*)src;
    *(__half2*)(dst)     = __floats2half2_rn(f.x, f.y);
    *(__half2*)(dst + 2) = __floats2half2_rn(f.z, f.w);
}

// ---------------------------------------------------------------------------
// K1: fused node GEMM on matrix cores + FUSED SCORE.
//   [X_init | X_feat] = X @ [Wx^T | Wv^T] + bias;  wexp = exp(lrelu(Xf.a))
// Block = 64 rows x 256 cols, 4 waves. A: fp32->fp16 LDS, XOR-swizzled.
// B: 16 half8 frags hoisted from 64 KB L2-resident Wf16.
// fp16 outputs repacked through LDS; the repacked tile is reused to compute
// the attention score dot-product (4 thr/row + 2 shfl_xor), killing k_score.
// ---------------------------------------------------------------------------
__global__ __launch_bounds__(256) void k_node_gemm(
    const float* __restrict__ X, const __half* __restrict__ Wf16,
    const float* __restrict__ Wxb, const float* __restrict__ Wvb,
    const float* __restrict__ aw,
    float* __restrict__ Xinit, __half* __restrict__ Xf16,
    float* __restrict__ wexp)
{
    __shared__ char smem[64 * 256];   // 16 KB A-tile; reused for fp16 repack
    const int tid  = threadIdx.x;
    const int w    = tid >> 6;
    const int lane = tid & 63;
    const int bm   = blockIdx.x * 64;
    const int colbase = w * 64;               // 0,64,128,192
    const bool isInit = (colbase < D);
    const int r16 = lane & 15;
    const int hi  = lane >> 4;                // 0..3
    const int g8  = hi * 8;

    // ---- stage A tile: coalesced fp32 load -> fp16 -> swizzled LDS ----
    {
        const int r  = tid >> 2;              // 0..63
        int srow = bm + r; if (srow >= N_NODES) srow = N_NODES - 1;
        const float4* src = (const float4*)(X + (size_t)srow * D + (tid & 3) * 32);
        float4 f[8];
        #pragma unroll
        for (int j = 0; j < 8; ++j) f[j] = src[j];
        const int swz  = (r & 7) << 4;
        const int base = r * 256 + (tid & 3) * 64;
        #pragma unroll
        for (int j = 0; j < 4; ++j)
            *(half8*)(smem + ((base + j * 16) ^ swz)) = cvt8(f[2*j], f[2*j+1]);
    }

    // ---- hoist all 16 B fragments (fp16, L2-resident) ----
    half8 bf[4][4];
    #pragma unroll
    for (int ks = 0; ks < 4; ++ks)
        #pragma unroll
        for (int n = 0; n < 4; ++n)
            bf[ks][n] = *(const half8*)(Wf16 + (size_t)(colbase + n*16 + r16) * D
                                        + ks * 32 + g8);

    __syncthreads();

    floatx4 acc[4][4] = {};
    #pragma unroll
    for (int ks = 0; ks < 4; ++ks) {
        half8 a[4];
        #pragma unroll
        for (int m = 0; m < 4; ++m) {
            const int R = m * 16 + r16;
            a[m] = *(const half8*)(smem + ((R*256 + ks*64 + hi*16) ^ ((R&7)<<4)));
        }
        #pragma unroll
        for (int m = 0; m < 4; ++m)
            #pragma unroll
            for (int n = 0; n < 4; ++n)
                acc[m][n] = __builtin_amdgcn_mfma_f32_16x16x32_f16(
                    a[m], bf[ks][n], acc[m][n], 0, 0, 0);
    }

    const float* bias = isInit ? Wxb : Wvb;
    const int rq = hi * 4;

    __syncthreads();   // A-tile dead; smem reusable

    if (isInit) {
        // fp32 stores: 16-lane groups write aligned 64 B segments
        #pragma unroll
        for (int n = 0; n < 4; ++n) {
            const int c = (colbase & (D - 1)) + n * 16 + r16;
            const float bv = bias[c];
            #pragma unroll
            for (int m = 0; m < 4; ++m)
                #pragma unroll
                for (int q = 0; q < 4; ++q) {
                    const int row = bm + m * 16 + rq + q;
                    if (row < N_NODES)
                        Xinit[(size_t)row * D + c] = acc[m][n][q] + bv;
                }
        }
    } else {
        // scatter fp16 values into LDS tile [64 rows][128 halves]
        __half* sh = (__half*)smem;
        #pragma unroll
        for (int n = 0; n < 4; ++n) {
            const int lc = (colbase - D) + n * 16 + r16;   // 0..127
            const float bv = bias[(colbase & (D - 1)) + n * 16 + r16];
            #pragma unroll
            for (int m = 0; m < 4; ++m)
                #pragma unroll
                for (int q = 0; q < 4; ++q)
                    sh[(m * 16 + rq + q) * 128 + lc] =
                        __float2half(acc[m][n][q] + bv);
        }
    }
    __syncthreads();
    // coalesced Xf16 store + fused score (4 threads per row)
    {
        const int r   = tid >> 2;
        const int row = bm + r;
        const int q4  = tid & 3;
        if (row < N_NODES) {
            const char* src = smem + r * 256 + q4 * 64;
            __half* dst = Xf16 + (size_t)row * D + q4 * 32;
            float part = 0.f;
            #pragma unroll
            for (int j = 0; j < 4; ++j) {
                half8 h = *(const half8*)(src + j * 16);
                *(half8*)(dst + j * 8) = h;
                float4 a0 = *(const float4*)(aw + q4 * 32 + j * 8);
                float4 a1 = *(const float4*)(aw + q4 * 32 + j * 8 + 4);
                part += (float)h[0]*a0.x + (float)h[1]*a0.y
                      + (float)h[2]*a0.z + (float)h[3]*a0.w
                      + (float)h[4]*a1.x + (float)h[5]*a1.y
                      + (float)h[6]*a1.z + (float)h[7]*a1.w;
            }
            part += __shfl_xor(part, 1, 64);
            part += __shfl_xor(part, 2, 64);
            if (q4 == 0) {
                float l = (part > 0.f) ? part : NEG_SLOPE * part;
                wexp[row] = expf(l);
            }
        }
    }
}

// ---------------------------------------------------------------------------
// K3: edge histogram + within-(block,bin) rank via LDS atomics ONLY.
// ---------------------------------------------------------------------------
__global__ __launch_bounds__(256) void k_part_e(
    const int* __restrict__ E, int* __restrict__ part,
    unsigned short* __restrict__ re)
{
    __shared__ int h[BINS_E];
    const int b = blockIdx.x;
    const int c0 = blockIdx.y * BINS_E;
    const int i0 = b * CHUNK_E;
    for (int t = threadIdx.x; t < BINS_E; t += 256) h[t] = 0;
    __syncthreads();
    for (int i = threadIdx.x; i < CHUNK_E; i += 256) {
        int c = E[i0 + i] - c0;
        if (c >= 0 && c < BINS_E) {
            int r = atomicAdd(&h[c], 1);            // LDS atomic, returns rank
            re[i0 + i] = (unsigned short)r;
        }
    }
    __syncthreads();
    for (int t = threadIdx.x; t < BINS_E; t += 256)
        part[(size_t)b * N_EDGES + c0 + t] = h[t];
}

// ---------------------------------------------------------------------------
// K3b: node histogram + within-(block,bin) rank via LDS atomics ONLY.
// Replaces the memory-side-atomic k_rank_n (68 us, 23.5 G atomics/s).
// ---------------------------------------------------------------------------
__global__ __launch_bounds__(256) void k_part_n(
    const int* __restrict__ V, int* __restrict__ part,
    unsigned short* __restrict__ rn)
{
    __shared__ int h[BINS_N];
    const int b = blockIdx.x;
    const int c0 = blockIdx.y * BINS_N;
    const int i0 = b * CHUNK_N;
    for (int t = threadIdx.x; t < BINS_N; t += 256) h[t] = 0;
    __syncthreads();
    for (int i = threadIdx.x; i < CHUNK_N; i += 256) {
        int c = V[i0 + i] - c0;
        if (c >= 0 && c < BINS_N) {
            int r = atomicAdd(&h[c], 1);
            rn[i0 + i] = (unsigned short)r;
        }
    }
    __syncthreads();
    for (int t = threadIdx.x; t < BINS_N; t += 256)
        part[(size_t)b * N_NODES + c0 + t] = h[t];
}

// ---------------------------------------------------------------------------
// K5: per-bin exclusive prefix over chunks; emits per-bin totals. Generic.
// ---------------------------------------------------------------------------
__global__ __launch_bounds__(256) void k_tot(
    int* __restrict__ part, int* __restrict__ tot, int nbins, int nblk)
{
    int bin = blockIdx.x * 256 + threadIdx.x;
    if (bin >= nbins) return;
    int run = 0;
    for (int b = 0; b < nblk; ++b) {
        size_t idx = (size_t)b * nbins + bin;
        int v = part[idx];
        part[idx] = run;
        run += v;
    }
    tot[bin] = run;
}

// ---------------------------------------------------------------------------
// Multi-block scan, phase 1: per-block sums. 256 thr x 16 elems (int4).
// ---------------------------------------------------------------------------
__global__ __launch_bounds__(256) void k_scan_bsum(
    const int* __restrict__ cnt, int* __restrict__ bsum, int n)
{
    __shared__ int red[256];
    const int base = blockIdx.x * SC_PER_BLOCK + threadIdx.x * SCC;
    int s = 0;
    if (base + SCC <= n) {
        const int4* p4 = (const int4*)(cnt + base);
        #pragma unroll
        for (int j = 0; j < SCC / 4; ++j) {
            int4 v = p4[j];
            s += v.x + v.y + v.z + v.w;
        }
    } else {
        for (int i = base; i < n; ++i) s += cnt[i];
    }
    red[threadIdx.x] = s;
    __syncthreads();
    for (int d = 128; d > 0; d >>= 1) {
        if (threadIdx.x < d) red[threadIdx.x] += red[threadIdx.x + d];
        __syncthreads();
    }
    if (threadIdx.x == 0) bsum[blockIdx.x] = red[0];
}

// ---------------------------------------------------------------------------
// Phase 2: single small block turns bsum into exclusive block bases,
// writes total into off[n].  nb <= 1024.
// ---------------------------------------------------------------------------
__global__ __launch_bounds__(1024) void k_scan_bbase(
    int* __restrict__ bsum, int nb, int* __restrict__ off, int n)
{
    __shared__ int sums[1024];
    const int tid = threadIdx.x;
    sums[tid] = (tid < nb) ? bsum[tid] : 0;
    __syncthreads();
    for (int d = 1; d < 1024; d <<= 1) {
        int mine = sums[tid];
        int other = (tid >= d) ? sums[tid - d] : 0;
        __syncthreads();
        sums[tid] = mine + other;
        __syncthreads();
    }
    if (tid < nb) bsum[tid] = (tid > 0) ? sums[tid - 1] : 0;
    if (tid == 0) off[n] = sums[1023];
}

// ---------------------------------------------------------------------------
// Phase 3: per-block exclusive scan + block base -> off[i].
// ---------------------------------------------------------------------------
__global__ __launch_bounds__(256) void k_scan_out(
    const int* __restrict__ cnt, const int* __restrict__ bsum,
    int* __restrict__ off, int n)
{
    __shared__ int tsum[256];
    const int base = blockIdx.x * SC_PER_BLOCK + threadIdx.x * SCC;
    int vals[SCC];
    int s = 0;
    if (base + SCC <= n) {
        const int4* p4 = (const int4*)(cnt + base);
        #pragma unroll
        for (int j = 0; j < SCC / 4; ++j) {
            int4 v = p4[j];
            vals[4 * j + 0] = v.x; vals[4 * j + 1] = v.y;
            vals[4 * j + 2] = v.z; vals[4 * j + 3] = v.w;
            s += v.x + v.y + v.z + v.w;
        }
    } else {
        #pragma unroll
        for (int j = 0; j < SCC; ++j) {
            int i = base + j;
            vals[j] = (i < n) ? cnt[i] : 0;
            s += vals[j];
        }
    }
    tsum[threadIdx.x] = s;
    __syncthreads();
    for (int d = 1; d < 256; d <<= 1) {
        int mine = tsum[threadIdx.x];
        int other = (threadIdx.x >= d) ? tsum[threadIdx.x - d] : 0;
        __syncthreads();
        tsum[threadIdx.x] = mine + other;
        __syncthreads();
    }
    int run = bsum[blockIdx.x] + ((threadIdx.x > 0) ? tsum[threadIdx.x - 1] : 0);
    #pragma unroll
    for (int j = 0; j < SCC; ++j) {
        int i = base + j;
        if (i < n) { off[i] = run; run += vals[j]; }
    }
}

// ---------------------------------------------------------------------------
// K6: edge scatter, NO atomics. w gathered from 400 KB wexp table.
// ---------------------------------------------------------------------------
__global__ __launch_bounds__(256) void k_scatter_e(
    const int* __restrict__ V, const int* __restrict__ E,
    const float* __restrict__ wexp, const unsigned short* __restrict__ re,
    const int* __restrict__ eoff, const int* __restrict__ part,
    int2* __restrict__ epairs)
{
    __shared__ int base[BINS_E];
    const int b = blockIdx.x;
    const int c0 = blockIdx.y * BINS_E;
    const int i0 = b * CHUNK_E;
    for (int t = threadIdx.x; t < BINS_E; t += 256)
        base[t] = part[(size_t)b * N_EDGES + c0 + t] + eoff[c0 + t];
    __syncthreads();
    for (int i = threadIdx.x; i < CHUNK_E; i += 256) {
        int e = E[i0 + i];
        int c = e - c0;
        if (c >= 0 && c < BINS_E) {
            int v = V[i0 + i];
            float w = wexp[v];
            epairs[base[c] + re[i0 + i]] = make_int2(v, __float_as_int(w));
        }
    }
}

// ---------------------------------------------------------------------------
// K7: node scatter, NO atomics, chunked LDS-base (mirrors k_scatter_e).
// ---------------------------------------------------------------------------
__global__ __launch_bounds__(256) void k_scatter_n(
    const int* __restrict__ V, const int* __restrict__ E,
    const unsigned short* __restrict__ rn, const int* __restrict__ noff,
    const int* __restrict__ part, int* __restrict__ nedges)
{
    __shared__ int base[BINS_N];
    const int b = blockIdx.x;
    const int c0 = blockIdx.y * BINS_N;
    const int i0 = b * CHUNK_N;
    for (int t = threadIdx.x; t < BINS_N; t += 256)
        base[t] = part[(size_t)b * N_NODES + c0 + t] + noff[c0 + t];
    __syncthreads();
    for (int i = threadIdx.x; i < CHUNK_N; i += 256) {
        int c = V[i0 + i] - c0;
        if (c >= 0 && c < BINS_N)
            nedges[base[c] + rn[i0 + i]] = E[i0 + i];
    }
}

// ---------------------------------------------------------------------------
// helper: accumulate 8 dims (8 halves packed in a float4) with weight w
// ---------------------------------------------------------------------------
__device__ __forceinline__ void acc8h(float w, float4 raw, float (&a)[8])
{
    const __half2* h = (const __half2*)&raw;
    #pragma unroll
    for (int t = 0; t < 4; ++t) {
        float2 f = __half22float2(h[t]);
        a[2*t]   = fmaf(w, f.x, a[2*t]);
        a[2*t+1] = fmaf(w, f.y, a[2*t+1]);
    }
}

// ---------------------------------------------------------------------------
// K8: per-edge aggregation. ONE WAVE PER EDGE, FOUR 16-LANE SLOTS.
// Slot s (lanes 16s..16s+15) handles incidence j+s; each lane loads 16 B
// (8 dims) so ONE wave load instruction fetches FOUR rows. Slot partials
// combined with shfl_xor 16 then 32.
// ---------------------------------------------------------------------------
__global__ __launch_bounds__(256) void k_edge_agg(
    const int2* __restrict__ epairs, const int* __restrict__ eoff,
    const __half* __restrict__ Xf16, const float* __restrict__ S,
    float* __restrict__ emsg)
{
    const int wave = threadIdx.x >> 6, lane = threadIdx.x & 63;
    const int e = blockIdx.x * 4 + wave;
    if (e >= N_EDGES) return;
    const int beg = eoff[e], end = eoff[e + 1];
    const int slot = lane >> 4;          // 0..3
    const int sl = lane & 15;            // dims 8*sl .. 8*sl+7
    float a[8] = {};
    float dsum = 0.f;
    int j = beg;
    #pragma unroll 2
    for (; j + 3 < end; j += 4) {
        int2 p = epairs[j + slot];
        float w = __int_as_float(p.y);
        float4 r = *(const float4*)(Xf16 + (size_t)p.x * D + sl * 8);
        dsum += w;
        acc8h(w, r, a);
    }
    if (j + slot < end) {
        int2 p = epairs[j + slot];
        float w = __int_as_float(p.y);
        float4 r = *(const float4*)(Xf16 + (size_t)p.x * D + sl * 8);
        dsum += w;
        acc8h(w, r, a);
    }
    #pragma unroll
    for (int k = 0; k < 8; ++k) {
        a[k] += __shfl_xor(a[k], 16, 64);
        a[k] += __shfl_xor(a[k], 32, 64);
    }
    dsum += __shfl_xor(dsum, 16, 64);
    dsum += __shfl_xor(dsum, 32, 64);

    float inv = (end > beg) ? 1.f / dsum : 0.f;
    float y[8];
    #pragma unroll
    for (int k = 0; k < 8; ++k) {
        float t = a[k] * inv;
        y[k] = (t > 0.f) ? t : expm1f(t);
    }
    const size_t rb = (size_t)e * (D + STAR);
    if (slot == 0) {
        *(float4*)(emsg + rb + sl * 8)     = make_float4(y[0], y[1], y[2], y[3]);
        *(float4*)(emsg + rb + sl * 8 + 4) = make_float4(y[4], y[5], y[6], y[7]);
    } else if (slot == 1) {
        float4 s4 = *(const float4*)(S + (size_t)e * STAR + sl * 4);
        *(float4*)(emsg + rb + D + sl * 4) = s4;
    }
}

// ---------------------------------------------------------------------------
// K9: edge GEMM on matrix cores: Y = e_msg @ Wt^T + Wt_b -> fp16.
// ---------------------------------------------------------------------------
__global__ __launch_bounds__(256) void k_edge_gemm(
    const float* __restrict__ A, const __half* __restrict__ Wtf16,
    const float* __restrict__ Wtb, __half* __restrict__ Y16)
{
    __shared__ char smem[64 * 384];   // 24 KB A-tile; head reused for repack
    const int KDIM = D + STAR;        // 192
    const int tid  = threadIdx.x;
    const int w    = tid >> 6;
    const int lane = tid & 63;
    const int bm   = blockIdx.x * 64;
    const int colbase = w * 32;       // 0,32,64,96
    const int r16 = lane & 15;
    const int hi  = lane >> 4;
    const int g8  = hi * 8;

    // ---- stage A tile: 4 threads/row, 48 floats each (contiguous 768 B/row)
    {
        const int r = tid >> 2;
        int srow = bm + r; if (srow >= N_EDGES) srow = N_EDGES - 1;
        const float4* src = (const float4*)(A + (size_t)srow * KDIM + (tid & 3) * 48);
        float4 f[12];
        #pragma unroll
        for (int j = 0; j < 12; ++j) f[j] = src[j];
        const int swz  = (r & 7) << 4;
        const int base = r * 384 + (tid & 3) * 96;
        #pragma unroll
        for (int j = 0; j < 6; ++j)
            *(half8*)(smem + ((base + j * 16) ^ swz)) = cvt8(f[2*j], f[2*j+1]);
    }

    // ---- hoist 12 B fragments ----
    half8 bf[6][2];
    #pragma unroll
    for (int ks = 0; ks < 6; ++ks)
        #pragma unroll
        for (int n = 0; n < 2; ++n)
            bf[ks][n] = *(const half8*)(Wtf16 + (size_t)(colbase + n*16 + r16) * KDIM
                                        + ks * 32 + g8);

    __syncthreads();

    floatx4 acc[4][2] = {};
    #pragma unroll
    for (int ks = 0; ks < 6; ++ks) {
        half8 a[4];
        #pragma unroll
        for (int m = 0; m < 4; ++m) {
            const int R = m * 16 + r16;
            a[m] = *(const half8*)(smem + ((R*384 + ks*64 + hi*16) ^ ((R&7)<<4)));
        }
        #pragma unroll
        for (int m = 0; m < 4; ++m)
            #pragma unroll
            for (int n = 0; n < 2; ++n)
                acc[m][n] = __builtin_amdgcn_mfma_f32_16x16x32_f16(
                    a[m], bf[ks][n], acc[m][n], 0, 0, 0);
    }

    const int rq = hi * 4;
    __syncthreads();   // A-tile dead

    // scatter fp16 results into LDS tile [64 rows][128 halves]
    {
        __half* sh = (__half*)smem;
        #pragma unroll
        for (int n = 0; n < 2; ++n) {
            const int c = colbase + n * 16 + r16;     // 0..127
            const float bv = Wtb[c];
            #pragma unroll
            for (int m = 0; m < 4; ++m)
                #pragma unroll
                for (int q = 0; q < 4; ++q)
                    sh[(m * 16 + rq + q) * 128 + c] =
                        __float2half(acc[m][n][q] + bv);
        }
    }
    __syncthreads();
    // coalesced store: 64 rows x 256 B contiguous
    {
        const int r   = tid >> 2;
        const int row = bm + r;
        if (row < N_EDGES) {
            const char* src = smem + r * 256 + (tid & 3) * 64;
            __half* dst = Y16 + (size_t)row * D + (tid & 3) * 32;
            #pragma unroll
            for (int j = 0; j < 4; ++j)
                *(half8*)(dst + j * 8) = *(const half8*)(src + j * 16);
        }
    }
}

// ---------------------------------------------------------------------------
// K10: per-node aggregation. ONE WAVE PER NODE, FOUR 16-LANE SLOTS (as K8).
// out[v] = elu(mean_j Y[e_j]) + out[v]   (out holds X_init).
// ---------------------------------------------------------------------------
__global__ __launch_bounds__(256) void k_node_agg(
    const int* __restrict__ nedges, const int* __restrict__ noff,
    const __half* __restrict__ Y16, float* __restrict__ out)
{
    const int wave = threadIdx.x >> 6, lane = threadIdx.x & 63;
    const int v = blockIdx.x * 4 + wave;
    if (v >= N_NODES) return;
    const int beg = noff[v], end = noff[v + 1];
    const int slot = lane >> 4;
    const int sl = lane & 15;
    float a[8] = {};
    int j = beg;
    #pragma unroll 2
    for (; j + 3 < end; j += 4) {
        int e0 = nedges[j + slot];
        float4 r = *(const float4*)(Y16 + (size_t)e0 * D + sl * 8);
        acc8h(1.f, r, a);
    }
    if (j + slot < end) {
        int e0 = nedges[j + slot];
        float4 r = *(const float4*)(Y16 + (size_t)e0 * D + sl * 8);
        acc8h(1.f, r, a);
    }
    #pragma unroll
    for (int k = 0; k < 8; ++k) {
        a[k] += __shfl_xor(a[k], 16, 64);
        a[k] += __shfl_xor(a[k], 32, 64);
    }

    if (slot == 0) {
        int cnt = end - beg;
        float invc = 1.f / (float)max(cnt, 1);
        float x[8];
        #pragma unroll
        for (int k = 0; k < 8; ++k) {
            float t = a[k] * invc;
            x[k] = (t > 0.f) ? t : expm1f(t);
        }
        float4* o0 = (float4*)(out + (size_t)v * D + sl * 8);
        float4* o1 = (float4*)(out + (size_t)v * D + sl * 8 + 4);
        float4 c0 = *o0, c1 = *o1;
        *o0 = make_float4(c0.x + x[0], c0.y + x[1], c0.z + x[2], c0.w + x[3]);
        *o1 = make_float4(c1.x + x[4], c1.y + x[5], c1.z + x[6], c1.w + x[7]);
    }
}

// ---------------------------------------------------------------------------
extern "C" void kernel_launch(void* const* d_in, const int* in_sizes, int n_in,
                              void* d_out, int out_size, void* d_ws, size_t ws_size,
                              hipStream_t stream)
{
    const float* X    = (const float*)d_in[0];
    const int*   V    = (const int*)  d_in[1];
    const int*   E    = (const int*)  d_in[2];
    const float* S    = (const float*)d_in[3];
    const float* Wx_w = (const float*)d_in[4];
    const float* Wx_b = (const float*)d_in[5];
    const float* Wv_w = (const float*)d_in[6];
    const float* Wv_b = (const float*)d_in[7];
    const float* a_w  = (const float*)d_in[8];
    const float* Wt_w = (const float*)d_in[9];
    const float* Wt_b = (const float*)d_in[10];
    float* out = (float*)d_out;

    char* p = (char*)d_ws;
    auto take = [&](size_t bytes) -> char* {
        char* r = p;
        p += (bytes + 255) & ~(size_t)255;
        return r;
    };

    __half* Xf16  = (__half*)take((size_t)N_NODES * D * 2);
    float*  wexp  = (float*) take((size_t)N_NODES * 4);
    int*    part_e = (int*)  take((size_t)NBLK_E * N_EDGES * 4);
    int*    part_n = (int*)  take((size_t)NBLK_N * N_NODES * 4);
    int*    tot_e = (int*)   take((size_t)N_EDGES * 4);
    int*    tot_n = (int*)   take((size_t)N_NODES * 4);
    int*    eoff  = (int*)   take((size_t)(N_EDGES + 1) * 4);
    int*    noff  = (int*)   take((size_t)(N_NODES + 1) * 4);
    int*    bsum_e = (int*)  take((size_t)SC_NBLK(N_EDGES) * 4);
    int*    bsum_n = (int*)  take((size_t)SC_NBLK(N_NODES) * 4);
    unsigned short* re = (unsigned short*)take((size_t)NNZ * 2);
    unsigned short* rn = (unsigned short*)take((size_t)NNZ * 2);
    int2*   epairs = (int2*) take((size_t)NNZ * 8);
    int*    nedges = (int*)  take((size_t)NNZ * 4);
    float*  emsg  = (float*) take((size_t)N_EDGES * (D + STAR) * 4);
    __half* Y16   = (__half*)take((size_t)N_EDGES * D * 2);
    __half* Wf16  = (__half*)take((size_t)256 * D * 2);          // [Wx;Wv] fp16
    __half* Wtf16 = (__half*)take((size_t)D * (D + STAR) * 2);   // Wt fp16

    k_cvt_w<<<56, 256, 0, stream>>>(Wx_w, Wv_w, Wt_w, Wf16, Wtf16);

    k_node_gemm<<<(N_NODES + 63) / 64, 256, 0, stream>>>(
        X, Wf16, Wx_b, Wv_b, a_w, out, Xf16, wexp);

    k_part_e<<<dim3(NBLK_E, 2), 256, 0, stream>>>(E, part_e, re);
    k_part_n<<<dim3(NBLK_N, NPASS_N), 256, 0, stream>>>(V, part_n, rn);

    k_tot<<<(N_EDGES + 255) / 256, 256, 0, stream>>>(part_e, tot_e,
                                                     N_EDGES, NBLK_E);
    k_tot<<<(N_NODES + 255) / 256, 256, 0, stream>>>(part_n, tot_n,
                                                     N_NODES, NBLK_N);

    // edge scan (n = 20000, 5 blocks)
    k_scan_bsum<<<SC_NBLK(N_EDGES), 256, 0, stream>>>(tot_e, bsum_e, N_EDGES);
    k_scan_bbase<<<1, 1024, 0, stream>>>(bsum_e, SC_NBLK(N_EDGES), eoff, N_EDGES);
    k_scan_out<<<SC_NBLK(N_EDGES), 256, 0, stream>>>(tot_e, bsum_e, eoff, N_EDGES);

    // node scan (n = 100000, 25 blocks)
    k_scan_bsum<<<SC_NBLK(N_NODES), 256, 0, stream>>>(tot_n, bsum_n, N_NODES);
    k_scan_bbase<<<1, 1024, 0, stream>>>(bsum_n, SC_NBLK(N_NODES), noff, N_NODES);
    k_scan_out<<<SC_NBLK(N_NODES), 256, 0, stream>>>(tot_n, bsum_n, noff, N_NODES);

    k_scatter_e<<<dim3(NBLK_E, 2), 256, 0, stream>>>(V, E, wexp, re, eoff,
                                                     part_e, epairs);
    k_scatter_n<<<dim3(NBLK_N, NPASS_N), 256, 0, stream>>>(V, E, rn, noff,
                                                           part_n, nedges);

    k_edge_agg<<<(N_EDGES + 3) / 4, 256, 0, stream>>>(epairs, eoff, Xf16, S, emsg);

    k_edge_gemm<<<(N_EDGES + 63) / 64, 256, 0, stream>>>(emsg, Wtf16, Wt_b, Y16);

    k_node_agg<<<(N_NODES + 3) / 4, 256, 0, stream>>>(nedges, noff, Y16, out);
}

// Round 7
// 534.773 us; speedup vs baseline: 1.1256x; 1.1256x over previous
//
#include <hip/hip_runtime.h>
#include <hip/hip_bf16.h>
#include <hip/hip_fp16.h>

#define N_NODES 100000
#define N_EDGES 20000
#define NNZ     1600000
#define D       128
#define STAR    64
#define NEG_SLOPE 0.2f

// edge counting-sort: SINGLE pass, 20000 bins packed as 2xushort per int (40 KB).
#define NBLK_E  400
#define CHUNK_E 4000        // NNZ / NBLK_E
#define H32_E   10000       // ints = 20000 packed ushort bins

// node counting-sort: 5 passes of 20000 packed-ushort bins (40 KB LDS).
#define NBLK_N  64
#define CHUNK_N 25000       // NNZ / NBLK_N
#define BINS_N  20000
#define H32_N   10000
#define NPASS_N 5

// multi-block scan: 256 threads x 16 elements
#define SCC 16
#define SC_PER_BLOCK (256 * SCC)   // 4096
#define SC_NBLK(n) (((n) + SC_PER_BLOCK - 1) / SC_PER_BLOCK)

typedef _Float16 half8 __attribute__((ext_vector_type(8)));
typedef float    floatx4 __attribute__((ext_vector_type(4)));

// pack 8 fp32 (two float4) -> half8 fragment
__device__ __forceinline__ half8 cvt8(float4 f0, float4 f1)
{
    half8 h;
    h[0] = (_Float16)f0.x; h[1] = (_Float16)f0.y;
    h[2] = (_Float16)f0.z; h[3] = (_Float16)f0.w;
    h[4] = (_Float16)f1.x; h[5] = (_Float16)f1.y;
    h[6] = (_Float16)f1.z; h[7] = (_Float16)f1.w;
    return h;
}

// ---------------------------------------------------------------------------
// K0: one-time fp32 -> fp16 weight conversion.
// ---------------------------------------------------------------------------
__global__ __launch_bounds__(256) void k_cvt_w(
    const float* __restrict__ Wx, const float* __restrict__ Wv,
    const float* __restrict__ Wt,
    __half* __restrict__ Wf16, __half* __restrict__ Wtf16)
{
    int i = (blockIdx.x * 256 + threadIdx.x) * 4;
    const float* src;
    __half* dst;
    if (i < 16384)            { src = Wx + i;         dst = Wf16 + i; }
    else if (i < 32768)       { src = Wv + (i-16384); dst = Wf16 + i; }
    else if (i < 32768+24576) { src = Wt + (i-32768); dst = Wtf16 + (i-32768); }
    else return;
    float4 f = *(const float4*)src;
    *(__half2*)(dst)     = __floats2half2_rn(f.x, f.y);
    *(__half2*)(dst + 2) = __floats2half2_rn(f.z, f.w);
}

// ---------------------------------------------------------------------------
// K1: fused node GEMM on matrix cores + FUSED SCORE.
//   [X_init | X_feat] = X @ [Wx^T | Wv^T] + bias;  wexp = exp(lrelu(Xf.a))
// ---------------------------------------------------------------------------
__global__ __launch_bounds__(256) void k_node_gemm(
    const float* __restrict__ X, const __half* __restrict__ Wf16,
    const float* __restrict__ Wxb, const float* __restrict__ Wvb,
    const float* __restrict__ aw,
    float* __restrict__ Xinit, __half* __restrict__ Xf16,
    float* __restrict__ wexp)
{
    __shared__ char smem[64 * 256];   // 16 KB A-tile; reused for fp16 repack
    const int tid  = threadIdx.x;
    const int w    = tid >> 6;
    const int lane = tid & 63;
    const int bm   = blockIdx.x * 64;
    const int colbase = w * 64;               // 0,64,128,192
    const bool isInit = (colbase < D);
    const int r16 = lane & 15;
    const int hi  = lane >> 4;                // 0..3
    const int g8  = hi * 8;

    // ---- stage A tile: coalesced fp32 load -> fp16 -> swizzled LDS ----
    {
        const int r  = tid >> 2;              // 0..63
        int srow = bm + r; if (srow >= N_NODES) srow = N_NODES - 1;
        const float4* src = (const float4*)(X + (size_t)srow * D + (tid & 3) * 32);
        float4 f[8];
        #pragma unroll
        for (int j = 0; j < 8; ++j) f[j] = src[j];
        const int swz  = (r & 7) << 4;
        const int base = r * 256 + (tid & 3) * 64;
        #pragma unroll
        for (int j = 0; j < 4; ++j)
            *(half8*)(smem + ((base + j * 16) ^ swz)) = cvt8(f[2*j], f[2*j+1]);
    }

    // ---- hoist all 16 B fragments (fp16, L2-resident) ----
    half8 bf[4][4];
    #pragma unroll
    for (int ks = 0; ks < 4; ++ks)
        #pragma unroll
        for (int n = 0; n < 4; ++n)
            bf[ks][n] = *(const half8*)(Wf16 + (size_t)(colbase + n*16 + r16) * D
                                        + ks * 32 + g8);

    __syncthreads();

    floatx4 acc[4][4] = {};
    #pragma unroll
    for (int ks = 0; ks < 4; ++ks) {
        half8 a[4];
        #pragma unroll
        for (int m = 0; m < 4; ++m) {
            const int R = m * 16 + r16;
            a[m] = *(const half8*)(smem + ((R*256 + ks*64 + hi*16) ^ ((R&7)<<4)));
        }
        #pragma unroll
        for (int m = 0; m < 4; ++m)
            #pragma unroll
            for (int n = 0; n < 4; ++n)
                acc[m][n] = __builtin_amdgcn_mfma_f32_16x16x32_f16(
                    a[m], bf[ks][n], acc[m][n], 0, 0, 0);
    }

    const float* bias = isInit ? Wxb : Wvb;
    const int rq = hi * 4;

    __syncthreads();   // A-tile dead; smem reusable

    if (isInit) {
        #pragma unroll
        for (int n = 0; n < 4; ++n) {
            const int c = (colbase & (D - 1)) + n * 16 + r16;
            const float bv = bias[c];
            #pragma unroll
            for (int m = 0; m < 4; ++m)
                #pragma unroll
                for (int q = 0; q < 4; ++q) {
                    const int row = bm + m * 16 + rq + q;
                    if (row < N_NODES)
                        Xinit[(size_t)row * D + c] = acc[m][n][q] + bv;
                }
        }
    } else {
        __half* sh = (__half*)smem;
        #pragma unroll
        for (int n = 0; n < 4; ++n) {
            const int lc = (colbase - D) + n * 16 + r16;   // 0..127
            const float bv = bias[(colbase & (D - 1)) + n * 16 + r16];
            #pragma unroll
            for (int m = 0; m < 4; ++m)
                #pragma unroll
                for (int q = 0; q < 4; ++q)
                    sh[(m * 16 + rq + q) * 128 + lc] =
                        __float2half(acc[m][n][q] + bv);
        }
    }
    __syncthreads();
    // coalesced Xf16 store + fused score (4 threads per row)
    {
        const int r   = tid >> 2;
        const int row = bm + r;
        const int q4  = tid & 3;
        if (row < N_NODES) {
            const char* src = smem + r * 256 + q4 * 64;
            __half* dst = Xf16 + (size_t)row * D + q4 * 32;
            float part = 0.f;
            #pragma unroll
            for (int j = 0; j < 4; ++j) {
                half8 h = *(const half8*)(src + j * 16);
                *(half8*)(dst + j * 8) = h;
                float4 a0 = *(const float4*)(aw + q4 * 32 + j * 8);
                float4 a1 = *(const float4*)(aw + q4 * 32 + j * 8 + 4);
                part += (float)h[0]*a0.x + (float)h[1]*a0.y
                      + (float)h[2]*a0.z + (float)h[3]*a0.w
                      + (float)h[4]*a1.x + (float)h[5]*a1.y
                      + (float)h[6]*a1.z + (float)h[7]*a1.w;
            }
            part += __shfl_xor(part, 1, 64);
            part += __shfl_xor(part, 2, 64);
            if (q4 == 0) {
                float l = (part > 0.f) ? part : NEG_SLOPE * part;
                wexp[row] = expf(l);
            }
        }
    }
}

// ---------------------------------------------------------------------------
// K3: edge histogram+rank, SINGLE pass, packed 2xushort-per-int LDS bins.
// rank = halfword of atomicAdd return. Counts per (chunk,bin) < 65536 always.
// ---------------------------------------------------------------------------
__global__ __launch_bounds__(256) void k_part_e(
    const int* __restrict__ E, unsigned short* __restrict__ part,
    unsigned short* __restrict__ re)
{
    __shared__ int h[H32_E];
    const int b = blockIdx.x;
    const int i0 = b * CHUNK_E;
    for (int t = threadIdx.x; t < H32_E; t += 256) h[t] = 0;
    __syncthreads();
    const int4* E4 = (const int4*)(E + i0);
    for (int i = threadIdx.x; i < CHUNK_E / 4; i += 256) {
        int4 q = E4[i];
        int ev[4] = {q.x, q.y, q.z, q.w};
        #pragma unroll
        for (int t = 0; t < 4; ++t) {
            int e = ev[t];
            unsigned sh = (e & 1) << 4;
            int old = atomicAdd(&h[e >> 1], 1 << sh);
            re[i0 + i * 4 + t] = (unsigned short)((unsigned)old >> sh);
        }
    }
    __syncthreads();
    int* dst = (int*)(part + (size_t)b * N_EDGES);
    for (int t = threadIdx.x; t < H32_E; t += 256) dst[t] = h[t];
}

// ---------------------------------------------------------------------------
// K3b: node histogram+rank, 5 passes x 20000 packed bins (40 KB LDS).
// ---------------------------------------------------------------------------
__global__ __launch_bounds__(256) void k_part_n(
    const int* __restrict__ V, unsigned short* __restrict__ part,
    unsigned short* __restrict__ rn)
{
    __shared__ int h[H32_N];
    const int b = blockIdx.x;
    const int c0 = blockIdx.y * BINS_N;
    const int i0 = b * CHUNK_N;
    for (int t = threadIdx.x; t < H32_N; t += 256) h[t] = 0;
    __syncthreads();
    const int4* V4 = (const int4*)(V + i0);
    for (int i = threadIdx.x; i < CHUNK_N / 4; i += 256) {
        int4 q = V4[i];
        int vv[4] = {q.x, q.y, q.z, q.w};
        #pragma unroll
        for (int t = 0; t < 4; ++t) {
            int c = vv[t] - c0;
            if ((unsigned)c < (unsigned)BINS_N) {
                unsigned sh = (c & 1) << 4;
                int old = atomicAdd(&h[c >> 1], 1 << sh);
                rn[i0 + i * 4 + t] = (unsigned short)((unsigned)old >> sh);
            }
        }
    }
    __syncthreads();
    int* dst = (int*)(part + (size_t)b * N_NODES + c0);
    for (int t = threadIdx.x; t < H32_N; t += 256) dst[t] = h[t];
}

// ---------------------------------------------------------------------------
// K5: per-bin exclusive prefix over chunks (ushort partials, int totals).
// ---------------------------------------------------------------------------
__global__ __launch_bounds__(256) void k_tot_u16(
    unsigned short* __restrict__ part, int* __restrict__ tot,
    int nbins, int nblk)
{
    int bin = blockIdx.x * 256 + threadIdx.x;
    if (bin >= nbins) return;
    int run = 0;
    for (int b = 0; b < nblk; ++b) {
        size_t idx = (size_t)b * nbins + bin;
        int v = part[idx];
        part[idx] = (unsigned short)run;
        run += v;
    }
    tot[bin] = run;
}

// ---------------------------------------------------------------------------
// Multi-block scan, phase 1: per-block sums. 256 thr x 16 elems (int4).
// ---------------------------------------------------------------------------
__global__ __launch_bounds__(256) void k_scan_bsum(
    const int* __restrict__ cnt, int* __restrict__ bsum, int n)
{
    __shared__ int red[256];
    const int base = blockIdx.x * SC_PER_BLOCK + threadIdx.x * SCC;
    int s = 0;
    if (base + SCC <= n) {
        const int4* p4 = (const int4*)(cnt + base);
        #pragma unroll
        for (int j = 0; j < SCC / 4; ++j) {
            int4 v = p4[j];
            s += v.x + v.y + v.z + v.w;
        }
    } else {
        for (int i = base; i < n; ++i) s += cnt[i];
    }
    red[threadIdx.x] = s;
    __syncthreads();
    for (int d = 128; d > 0; d >>= 1) {
        if (threadIdx.x < d) red[threadIdx.x] += red[threadIdx.x + d];
        __syncthreads();
    }
    if (threadIdx.x == 0) bsum[blockIdx.x] = red[0];
}

// ---------------------------------------------------------------------------
// Phase 2: exclusive block bases; writes total into off[n].  nb <= 1024.
// ---------------------------------------------------------------------------
__global__ __launch_bounds__(1024) void k_scan_bbase(
    int* __restrict__ bsum, int nb, int* __restrict__ off, int n)
{
    __shared__ int sums[1024];
    const int tid = threadIdx.x;
    sums[tid] = (tid < nb) ? bsum[tid] : 0;
    __syncthreads();
    for (int d = 1; d < 1024; d <<= 1) {
        int mine = sums[tid];
        int other = (tid >= d) ? sums[tid - d] : 0;
        __syncthreads();
        sums[tid] = mine + other;
        __syncthreads();
    }
    if (tid < nb) bsum[tid] = (tid > 0) ? sums[tid - 1] : 0;
    if (tid == 0) off[n] = sums[1023];
}

// ---------------------------------------------------------------------------
// Phase 3: per-block exclusive scan + block base -> off[i].
// ---------------------------------------------------------------------------
__global__ __launch_bounds__(256) void k_scan_out(
    const int* __restrict__ cnt, const int* __restrict__ bsum,
    int* __restrict__ off, int n)
{
    __shared__ int tsum[256];
    const int base = blockIdx.x * SC_PER_BLOCK + threadIdx.x * SCC;
    int vals[SCC];
    int s = 0;
    if (base + SCC <= n) {
        const int4* p4 = (const int4*)(cnt + base);
        #pragma unroll
        for (int j = 0; j < SCC / 4; ++j) {
            int4 v = p4[j];
            vals[4 * j + 0] = v.x; vals[4 * j + 1] = v.y;
            vals[4 * j + 2] = v.z; vals[4 * j + 3] = v.w;
            s += v.x + v.y + v.z + v.w;
        }
    } else {
        #pragma unroll
        for (int j = 0; j < SCC; ++j) {
            int i = base + j;
            vals[j] = (i < n) ? cnt[i] : 0;
            s += vals[j];
        }
    }
    tsum[threadIdx.x] = s;
    __syncthreads();
    for (int d = 1; d < 256; d <<= 1) {
        int mine = tsum[threadIdx.x];
        int other = (threadIdx.x >= d) ? tsum[threadIdx.x - d] : 0;
        __syncthreads();
        tsum[threadIdx.x] = mine + other;
        __syncthreads();
    }
    int run = bsum[blockIdx.x] + ((threadIdx.x > 0) ? tsum[threadIdx.x - 1] : 0);
    #pragma unroll
    for (int j = 0; j < SCC; ++j) {
        int i = base + j;
        if (i < n) { off[i] = run; run += vals[j]; }
    }
}

// ---------------------------------------------------------------------------
// K6: FUSED flat scatter (edge + node), NO atomics, NO LDS.
// pos_e = eoff[e] + part_e[i/CHUNK_E][e] + re[i]   -> epairs
// pos_n = noff[v] + part_n[i/CHUNK_N][v] + rn[i]   -> nedges
// ---------------------------------------------------------------------------
__global__ __launch_bounds__(256) void k_scatter_both(
    const int* __restrict__ V, const int* __restrict__ E,
    const unsigned short* __restrict__ re, const unsigned short* __restrict__ rn,
    const unsigned short* __restrict__ part_e,
    const unsigned short* __restrict__ part_n,
    const int* __restrict__ eoff, const int* __restrict__ noff,
    const float* __restrict__ wexp,
    int2* __restrict__ epairs, int* __restrict__ nedges)
{
    int i = blockIdx.x * 256 + threadIdx.x;
    if (i >= NNZ) return;
    int e = E[i], v = V[i];
    int be = i / CHUNK_E;
    int bn = i / CHUNK_N;
    int pe = eoff[e] + part_e[(size_t)be * N_EDGES + e] + re[i];
    int pn = noff[v] + part_n[(size_t)bn * N_NODES + v] + rn[i];
    float w = wexp[v];
    epairs[pe] = make_int2(v, __float_as_int(w));
    nedges[pn] = e;
}

// ---------------------------------------------------------------------------
// helper: accumulate 8 dims (8 halves packed in a float4) with weight w
// ---------------------------------------------------------------------------
__device__ __forceinline__ void acc8h(float w, float4 raw, float (&a)[8])
{
    const __half2* h = (const __half2*)&raw;
    #pragma unroll
    for (int t = 0; t < 4; ++t) {
        float2 f = __half22float2(h[t]);
        a[2*t]   = fmaf(w, f.x, a[2*t]);
        a[2*t+1] = fmaf(w, f.y, a[2*t+1]);
    }
}

// ---------------------------------------------------------------------------
// K8: per-edge aggregation. ONE WAVE PER EDGE, FOUR 16-LANE SLOTS.
// ---------------------------------------------------------------------------
__global__ __launch_bounds__(256) void k_edge_agg(
    const int2* __restrict__ epairs, const int* __restrict__ eoff,
    const __half* __restrict__ Xf16, const float* __restrict__ S,
    float* __restrict__ emsg)
{
    const int wave = threadIdx.x >> 6, lane = threadIdx.x & 63;
    const int e = blockIdx.x * 4 + wave;
    if (e >= N_EDGES) return;
    const int beg = eoff[e], end = eoff[e + 1];
    const int slot = lane >> 4;          // 0..3
    const int sl = lane & 15;            // dims 8*sl .. 8*sl+7
    float a[8] = {};
    float dsum = 0.f;
    int j = beg;
    #pragma unroll 2
    for (; j + 3 < end; j += 4) {
        int2 p = epairs[j + slot];
        float w = __int_as_float(p.y);
        float4 r = *(const float4*)(Xf16 + (size_t)p.x * D + sl * 8);
        dsum += w;
        acc8h(w, r, a);
    }
    if (j + slot < end) {
        int2 p = epairs[j + slot];
        float w = __int_as_float(p.y);
        float4 r = *(const float4*)(Xf16 + (size_t)p.x * D + sl * 8);
        dsum += w;
        acc8h(w, r, a);
    }
    #pragma unroll
    for (int k = 0; k < 8; ++k) {
        a[k] += __shfl_xor(a[k], 16, 64);
        a[k] += __shfl_xor(a[k], 32, 64);
    }
    dsum += __shfl_xor(dsum, 16, 64);
    dsum += __shfl_xor(dsum, 32, 64);

    float inv = (end > beg) ? 1.f / dsum : 0.f;
    float y[8];
    #pragma unroll
    for (int k = 0; k < 8; ++k) {
        float t = a[k] * inv;
        y[k] = (t > 0.f) ? t : expm1f(t);
    }
    const size_t rb = (size_t)e * (D + STAR);
    if (slot == 0) {
        *(float4*)(emsg + rb + sl * 8)     = make_float4(y[0], y[1], y[2], y[3]);
        *(float4*)(emsg + rb + sl * 8 + 4) = make_float4(y[4], y[5], y[6], y[7]);
    } else if (slot == 1) {
        float4 s4 = *(const float4*)(S + (size_t)e * STAR + sl * 4);
        *(float4*)(emsg + rb + D + sl * 4) = s4;
    }
}

// ---------------------------------------------------------------------------
// K9: edge GEMM on matrix cores: Y = e_msg @ Wt^T + Wt_b -> fp16.
// ---------------------------------------------------------------------------
__global__ __launch_bounds__(256) void k_edge_gemm(
    const float* __restrict__ A, const __half* __restrict__ Wtf16,
    const float* __restrict__ Wtb, __half* __restrict__ Y16)
{
    __shared__ char smem[64 * 384];   // 24 KB A-tile; head reused for repack
    const int KDIM = D + STAR;        // 192
    const int tid  = threadIdx.x;
    const int w    = tid >> 6;
    const int lane = tid & 63;
    const int bm   = blockIdx.x * 64;
    const int colbase = w * 32;       // 0,32,64,96
    const int r16 = lane & 15;
    const int hi  = lane >> 4;
    const int g8  = hi * 8;

    {
        const int r = tid >> 2;
        int srow = bm + r; if (srow >= N_EDGES) srow = N_EDGES - 1;
        const float4* src = (const float4*)(A + (size_t)srow * KDIM + (tid & 3) * 48);
        float4 f[12];
        #pragma unroll
        for (int j = 0; j < 12; ++j) f[j] = src[j];
        const int swz  = (r & 7) << 4;
        const int base = r * 384 + (tid & 3) * 96;
        #pragma unroll
        for (int j = 0; j < 6; ++j)
            *(half8*)(smem + ((base + j * 16) ^ swz)) = cvt8(f[2*j], f[2*j+1]);
    }

    half8 bf[6][2];
    #pragma unroll
    for (int ks = 0; ks < 6; ++ks)
        #pragma unroll
        for (int n = 0; n < 2; ++n)
            bf[ks][n] = *(const half8*)(Wtf16 + (size_t)(colbase + n*16 + r16) * KDIM
                                        + ks * 32 + g8);

    __syncthreads();

    floatx4 acc[4][2] = {};
    #pragma unroll
    for (int ks = 0; ks < 6; ++ks) {
        half8 a[4];
        #pragma unroll
        for (int m = 0; m < 4; ++m) {
            const int R = m * 16 + r16;
            a[m] = *(const half8*)(smem + ((R*384 + ks*64 + hi*16) ^ ((R&7)<<4)));
        }
        #pragma unroll
        for (int m = 0; m < 4; ++m)
            #pragma unroll
            for (int n = 0; n < 2; ++n)
                acc[m][n] = __builtin_amdgcn_mfma_f32_16x16x32_f16(
                    a[m], bf[ks][n], acc[m][n], 0, 0, 0);
    }

    const int rq = hi * 4;
    __syncthreads();   // A-tile dead

    {
        __half* sh = (__half*)smem;
        #pragma unroll
        for (int n = 0; n < 2; ++n) {
            const int c = colbase + n * 16 + r16;     // 0..127
            const float bv = Wtb[c];
            #pragma unroll
            for (int m = 0; m < 4; ++m)
                #pragma unroll
                for (int q = 0; q < 4; ++q)
                    sh[(m * 16 + rq + q) * 128 + c] =
                        __float2half(acc[m][n][q] + bv);
        }
    }
    __syncthreads();
    {
        const int r   = tid >> 2;
        const int row = bm + r;
        if (row < N_EDGES) {
            const char* src = smem + r * 256 + (tid & 3) * 64;
            __half* dst = Y16 + (size_t)row * D + (tid & 3) * 32;
            #pragma unroll
            for (int j = 0; j < 4; ++j)
                *(half8*)(dst + j * 8) = *(const half8*)(src + j * 16);
        }
    }
}

// ---------------------------------------------------------------------------
// K10: per-node aggregation. ONE WAVE PER NODE, FOUR 16-LANE SLOTS.
// out[v] = elu(mean_j Y[e_j]) + out[v]   (out holds X_init).
// ---------------------------------------------------------------------------
__global__ __launch_bounds__(256) void k_node_agg(
    const int* __restrict__ nedges, const int* __restrict__ noff,
    const __half* __restrict__ Y16, float* __restrict__ out)
{
    const int wave = threadIdx.x >> 6, lane = threadIdx.x & 63;
    const int v = blockIdx.x * 4 + wave;
    if (v >= N_NODES) return;
    const int beg = noff[v], end = noff[v + 1];
    const int slot = lane >> 4;
    const int sl = lane & 15;
    float a[8] = {};
    int j = beg;
    #pragma unroll 2
    for (; j + 3 < end; j += 4) {
        int e0 = nedges[j + slot];
        float4 r = *(const float4*)(Y16 + (size_t)e0 * D + sl * 8);
        acc8h(1.f, r, a);
    }
    if (j + slot < end) {
        int e0 = nedges[j + slot];
        float4 r = *(const float4*)(Y16 + (size_t)e0 * D + sl * 8);
        acc8h(1.f, r, a);
    }
    #pragma unroll
    for (int k = 0; k < 8; ++k) {
        a[k] += __shfl_xor(a[k], 16, 64);
        a[k] += __shfl_xor(a[k], 32, 64);
    }

    if (slot == 0) {
        int cnt = end - beg;
        float invc = 1.f / (float)max(cnt, 1);
        float x[8];
        #pragma unroll
        for (int k = 0; k < 8; ++k) {
            float t = a[k] * invc;
            x[k] = (t > 0.f) ? t : expm1f(t);
        }
        float4* o0 = (float4*)(out + (size_t)v * D + sl * 8);
        float4* o1 = (float4*)(out + (size_t)v * D + sl * 8 + 4);
        float4 c0 = *o0, c1 = *o1;
        *o0 = make_float4(c0.x + x[0], c0.y + x[1], c0.z + x[2], c0.w + x[3]);
        *o1 = make_float4(c1.x + x[4], c1.y + x[5], c1.z + x[6], c1.w + x[7]);
    }
}

// ---------------------------------------------------------------------------
extern "C" void kernel_launch(void* const* d_in, const int* in_sizes, int n_in,
                              void* d_out, int out_size, void* d_ws, size_t ws_size,
                              hipStream_t stream)
{
    const float* X    = (const float*)d_in[0];
    const int*   V    = (const int*)  d_in[1];
    const int*   E    = (const int*)  d_in[2];
    const float* S    = (const float*)d_in[3];
    const float* Wx_w = (const float*)d_in[4];
    const float* Wx_b = (const float*)d_in[5];
    const float* Wv_w = (const float*)d_in[6];
    const float* Wv_b = (const float*)d_in[7];
    const float* a_w  = (const float*)d_in[8];
    const float* Wt_w = (const float*)d_in[9];
    const float* Wt_b = (const float*)d_in[10];
    float* out = (float*)d_out;

    char* p = (char*)d_ws;
    auto take = [&](size_t bytes) -> char* {
        char* r = p;
        p += (bytes + 255) & ~(size_t)255;
        return r;
    };

    __half* Xf16  = (__half*)take((size_t)N_NODES * D * 2);
    float*  wexp  = (float*) take((size_t)N_NODES * 4);
    unsigned short* part_e = (unsigned short*)take((size_t)NBLK_E * N_EDGES * 2);
    unsigned short* part_n = (unsigned short*)take((size_t)NBLK_N * N_NODES * 2);
    int*    tot_e = (int*)   take((size_t)N_EDGES * 4);
    int*    tot_n = (int*)   take((size_t)N_NODES * 4);
    int*    eoff  = (int*)   take((size_t)(N_EDGES + 1) * 4);
    int*    noff  = (int*)   take((size_t)(N_NODES + 1) * 4);
    int*    bsum_e = (int*)  take((size_t)SC_NBLK(N_EDGES) * 4);
    int*    bsum_n = (int*)  take((size_t)SC_NBLK(N_NODES) * 4);
    unsigned short* re = (unsigned short*)take((size_t)NNZ * 2);
    unsigned short* rn = (unsigned short*)take((size_t)NNZ * 2);
    int2*   epairs = (int2*) take((size_t)NNZ * 8);
    int*    nedges = (int*)  take((size_t)NNZ * 4);
    float*  emsg  = (float*) take((size_t)N_EDGES * (D + STAR) * 4);
    __half* Y16   = (__half*)take((size_t)N_EDGES * D * 2);
    __half* Wf16  = (__half*)take((size_t)256 * D * 2);          // [Wx;Wv] fp16
    __half* Wtf16 = (__half*)take((size_t)D * (D + STAR) * 2);   // Wt fp16

    k_cvt_w<<<56, 256, 0, stream>>>(Wx_w, Wv_w, Wt_w, Wf16, Wtf16);

    k_node_gemm<<<(N_NODES + 63) / 64, 256, 0, stream>>>(
        X, Wf16, Wx_b, Wv_b, a_w, out, Xf16, wexp);

    k_part_e<<<NBLK_E, 256, 0, stream>>>(E, part_e, re);
    k_part_n<<<dim3(NBLK_N, NPASS_N), 256, 0, stream>>>(V, part_n, rn);

    k_tot_u16<<<(N_EDGES + 255) / 256, 256, 0, stream>>>(part_e, tot_e,
                                                         N_EDGES, NBLK_E);
    k_tot_u16<<<(N_NODES + 255) / 256, 256, 0, stream>>>(part_n, tot_n,
                                                         N_NODES, NBLK_N);

    // edge scan (n = 20000, 5 blocks)
    k_scan_bsum<<<SC_NBLK(N_EDGES), 256, 0, stream>>>(tot_e, bsum_e, N_EDGES);
    k_scan_bbase<<<1, 1024, 0, stream>>>(bsum_e, SC_NBLK(N_EDGES), eoff, N_EDGES);
    k_scan_out<<<SC_NBLK(N_EDGES), 256, 0, stream>>>(tot_e, bsum_e, eoff, N_EDGES);

    // node scan (n = 100000, 25 blocks)
    k_scan_bsum<<<SC_NBLK(N_NODES), 256, 0, stream>>>(tot_n, bsum_n, N_NODES);
    k_scan_bbase<<<1, 1024, 0, stream>>>(bsum_n, SC_NBLK(N_NODES), noff, N_NODES);
    k_scan_out<<<SC_NBLK(N_NODES), 256, 0, stream>>>(tot_n, bsum_n, noff, N_NODES);

    k_scatter_both<<<(NNZ + 255) / 256, 256, 0, stream>>>(
        V, E, re, rn, part_e, part_n, eoff, noff, wexp, epairs, nedges);

    k_edge_agg<<<(N_EDGES + 3) / 4, 256, 0, stream>>>(epairs, eoff, Xf16, S, emsg);

    k_edge_gemm<<<(N_EDGES + 63) / 64, 256, 0, stream>>>(emsg, Wtf16, Wt_b, Y16);

    k_node_agg<<<(N_NODES + 3) / 4, 256, 0, stream>>>(nedges, noff, Y16, out);
}

// Round 8
// 462.201 us; speedup vs baseline: 1.3023x; 1.1570x over previous
//
#include <hip/hip_runtime.h>
#include <hip/hip_bf16.h>
#include <hip/hip_fp16.h>

#define N_NODES 100000
#define N_EDGES 20000
#define NNZ     1600000
#define D       128
#define STAR    64
#define NEG_SLOPE 0.2f

// edge counting-sort: SINGLE pass, 20000 bins packed as 2xushort per int (40 KB).
#define NBLK_E  400
#define CHUNK_E 4000        // NNZ / NBLK_E
#define H32_E   10000       // ints = 20000 packed ushort bins

// node counting-sort: 5 passes of 20000 packed-ushort bins (40 KB LDS).
#define NBLK_N  64
#define CHUNK_N 25000       // NNZ / NBLK_N
#define BINS_N  20000
#define H32_N   10000
#define NPASS_N 5

// two-level chunk scan: 8 groups for both partitions
#define NGRP    8
#define CPG_E   (NBLK_E / NGRP)   // 50 chunks per group
#define CPG_N   (NBLK_N / NGRP)   // 8 chunks per group
// incidences per group = CPG_E*CHUNK_E = CPG_N*CHUNK_N = 200000 for both

// multi-block scan: 256 threads x 16 elements
#define SCC 16
#define SC_PER_BLOCK (256 * SCC)   // 4096
#define SC_NBLK(n) (((n) + SC_PER_BLOCK - 1) / SC_PER_BLOCK)

typedef _Float16 half8 __attribute__((ext_vector_type(8)));
typedef float    floatx4 __attribute__((ext_vector_type(4)));

// pack 8 fp32 (two float4) -> half8 fragment
__device__ __forceinline__ half8 cvt8(float4 f0, float4 f1)
{
    half8 h;
    h[0] = (_Float16)f0.x; h[1] = (_Float16)f0.y;
    h[2] = (_Float16)f0.z; h[3] = (_Float16)f0.w;
    h[4] = (_Float16)f1.x; h[5] = (_Float16)f1.y;
    h[6] = (_Float16)f1.z; h[7] = (_Float16)f1.w;
    return h;
}

// ---------------------------------------------------------------------------
// K0: one-time fp32 -> fp16 weight conversion.
// ---------------------------------------------------------------------------
__global__ __launch_bounds__(256) void k_cvt_w(
    const float* __restrict__ Wx, const float* __restrict__ Wv,
    const float* __restrict__ Wt,
    __half* __restrict__ Wf16, __half* __restrict__ Wtf16)
{
    int i = (blockIdx.x * 256 + threadIdx.x) * 4;
    const float* src;
    __half* dst;
    if (i < 16384)            { src = Wx + i;         dst = Wf16 + i; }
    else if (i < 32768)       { src = Wv + (i-16384); dst = Wf16 + i; }
    else if (i < 32768+24576) { src = Wt + (i-32768); dst = Wtf16 + (i-32768); }
    else return;
    float4 f = *(const float4*)src;
    *(__half2*)(dst)     = __floats2half2_rn(f.x, f.y);
    *(__half2*)(dst + 2) = __floats2half2_rn(f.z, f.w);
}

// ---------------------------------------------------------------------------
// K1: fused node GEMM on matrix cores + FUSED SCORE.
//   [X_init | X_feat] = X @ [Wx^T | Wv^T] + bias;  wexp = exp(lrelu(Xf.a))
// ---------------------------------------------------------------------------
__global__ __launch_bounds__(256) void k_node_gemm(
    const float* __restrict__ X, const __half* __restrict__ Wf16,
    const float* __restrict__ Wxb, const float* __restrict__ Wvb,
    const float* __restrict__ aw,
    float* __restrict__ Xinit, __half* __restrict__ Xf16,
    float* __restrict__ wexp)
{
    __shared__ char smem[64 * 256];   // 16 KB A-tile; reused for fp16 repack
    const int tid  = threadIdx.x;
    const int w    = tid >> 6;
    const int lane = tid & 63;
    const int bm   = blockIdx.x * 64;
    const int colbase = w * 64;               // 0,64,128,192
    const bool isInit = (colbase < D);
    const int r16 = lane & 15;
    const int hi  = lane >> 4;                // 0..3
    const int g8  = hi * 8;

    // ---- stage A tile: coalesced fp32 load -> fp16 -> swizzled LDS ----
    {
        const int r  = tid >> 2;              // 0..63
        int srow = bm + r; if (srow >= N_NODES) srow = N_NODES - 1;
        const float4* src = (const float4*)(X + (size_t)srow * D + (tid & 3) * 32);
        float4 f[8];
        #pragma unroll
        for (int j = 0; j < 8; ++j) f[j] = src[j];
        const int swz  = (r & 7) << 4;
        const int base = r * 256 + (tid & 3) * 64;
        #pragma unroll
        for (int j = 0; j < 4; ++j)
            *(half8*)(smem + ((base + j * 16) ^ swz)) = cvt8(f[2*j], f[2*j+1]);
    }

    // ---- hoist all 16 B fragments (fp16, L2-resident) ----
    half8 bf[4][4];
    #pragma unroll
    for (int ks = 0; ks < 4; ++ks)
        #pragma unroll
        for (int n = 0; n < 4; ++n)
            bf[ks][n] = *(const half8*)(Wf16 + (size_t)(colbase + n*16 + r16) * D
                                        + ks * 32 + g8);

    __syncthreads();

    floatx4 acc[4][4] = {};
    #pragma unroll
    for (int ks = 0; ks < 4; ++ks) {
        half8 a[4];
        #pragma unroll
        for (int m = 0; m < 4; ++m) {
            const int R = m * 16 + r16;
            a[m] = *(const half8*)(smem + ((R*256 + ks*64 + hi*16) ^ ((R&7)<<4)));
        }
        #pragma unroll
        for (int m = 0; m < 4; ++m)
            #pragma unroll
            for (int n = 0; n < 4; ++n)
                acc[m][n] = __builtin_amdgcn_mfma_f32_16x16x32_f16(
                    a[m], bf[ks][n], acc[m][n], 0, 0, 0);
    }

    const float* bias = isInit ? Wxb : Wvb;
    const int rq = hi * 4;

    __syncthreads();   // A-tile dead; smem reusable

    if (isInit) {
        #pragma unroll
        for (int n = 0; n < 4; ++n) {
            const int c = (colbase & (D - 1)) + n * 16 + r16;
            const float bv = bias[c];
            #pragma unroll
            for (int m = 0; m < 4; ++m)
                #pragma unroll
                for (int q = 0; q < 4; ++q) {
                    const int row = bm + m * 16 + rq + q;
                    if (row < N_NODES)
                        Xinit[(size_t)row * D + c] = acc[m][n][q] + bv;
                }
        }
    } else {
        __half* sh = (__half*)smem;
        #pragma unroll
        for (int n = 0; n < 4; ++n) {
            const int lc = (colbase - D) + n * 16 + r16;   // 0..127
            const float bv = bias[(colbase & (D - 1)) + n * 16 + r16];
            #pragma unroll
            for (int m = 0; m < 4; ++m)
                #pragma unroll
                for (int q = 0; q < 4; ++q)
                    sh[(m * 16 + rq + q) * 128 + lc] =
                        __float2half(acc[m][n][q] + bv);
        }
    }
    __syncthreads();
    // coalesced Xf16 store + fused score (4 threads per row)
    {
        const int r   = tid >> 2;
        const int row = bm + r;
        const int q4  = tid & 3;
        if (row < N_NODES) {
            const char* src = smem + r * 256 + q4 * 64;
            __half* dst = Xf16 + (size_t)row * D + q4 * 32;
            float part = 0.f;
            #pragma unroll
            for (int j = 0; j < 4; ++j) {
                half8 h = *(const half8*)(src + j * 16);
                *(half8*)(dst + j * 8) = h;
                float4 a0 = *(const float4*)(aw + q4 * 32 + j * 8);
                float4 a1 = *(const float4*)(aw + q4 * 32 + j * 8 + 4);
                part += (float)h[0]*a0.x + (float)h[1]*a0.y
                      + (float)h[2]*a0.z + (float)h[3]*a0.w
                      + (float)h[4]*a1.x + (float)h[5]*a1.y
                      + (float)h[6]*a1.z + (float)h[7]*a1.w;
            }
            part += __shfl_xor(part, 1, 64);
            part += __shfl_xor(part, 2, 64);
            if (q4 == 0) {
                float l = (part > 0.f) ? part : NEG_SLOPE * part;
                wexp[row] = expf(l);
            }
        }
    }
}

// ---------------------------------------------------------------------------
// K3: edge histogram+rank, SINGLE pass, packed 2xushort-per-int LDS bins.
// ---------------------------------------------------------------------------
__global__ __launch_bounds__(256) void k_part_e(
    const int* __restrict__ E, unsigned short* __restrict__ part,
    unsigned short* __restrict__ re)
{
    __shared__ int h[H32_E];
    const int b = blockIdx.x;
    const int i0 = b * CHUNK_E;
    for (int t = threadIdx.x; t < H32_E; t += 256) h[t] = 0;
    __syncthreads();
    const int4* E4 = (const int4*)(E + i0);
    for (int i = threadIdx.x; i < CHUNK_E / 4; i += 256) {
        int4 q = E4[i];
        int ev[4] = {q.x, q.y, q.z, q.w};
        #pragma unroll
        for (int t = 0; t < 4; ++t) {
            int e = ev[t];
            unsigned sh = (e & 1) << 4;
            int old = atomicAdd(&h[e >> 1], 1 << sh);
            re[i0 + i * 4 + t] = (unsigned short)((unsigned)old >> sh);
        }
    }
    __syncthreads();
    int* dst = (int*)(part + (size_t)b * N_EDGES);
    for (int t = threadIdx.x; t < H32_E; t += 256) dst[t] = h[t];
}

// ---------------------------------------------------------------------------
// K3b: node histogram+rank, 5 passes x 20000 packed bins (40 KB LDS).
// ---------------------------------------------------------------------------
__global__ __launch_bounds__(256) void k_part_n(
    const int* __restrict__ V, unsigned short* __restrict__ part,
    unsigned short* __restrict__ rn)
{
    __shared__ int h[H32_N];
    const int b = blockIdx.x;
    const int c0 = blockIdx.y * BINS_N;
    const int i0 = b * CHUNK_N;
    for (int t = threadIdx.x; t < H32_N; t += 256) h[t] = 0;
    __syncthreads();
    const int4* V4 = (const int4*)(V + i0);
    for (int i = threadIdx.x; i < CHUNK_N / 4; i += 256) {
        int4 q = V4[i];
        int vv[4] = {q.x, q.y, q.z, q.w};
        #pragma unroll
        for (int t = 0; t < 4; ++t) {
            int c = vv[t] - c0;
            if ((unsigned)c < (unsigned)BINS_N) {
                unsigned sh = (c & 1) << 4;
                int old = atomicAdd(&h[c >> 1], 1 << sh);
                rn[i0 + i * 4 + t] = (unsigned short)((unsigned)old >> sh);
            }
        }
    }
    __syncthreads();
    int* dst = (int*)(part + (size_t)b * N_NODES + c0);
    for (int t = threadIdx.x; t < H32_N; t += 256) dst[t] = h[t];
}

// ---------------------------------------------------------------------------
// K5a: within-GROUP exclusive scan over chunks (level 1 of 2).
// grid (bins/256, NGRP); each thread scans cpg chunks; emits gsum[g][bin].
// Replaces the 95 us serial 400-chain (3.3% occupancy) with 8x parallelism.
// ---------------------------------------------------------------------------
__global__ __launch_bounds__(256) void k_tot_grp(
    unsigned short* __restrict__ part, int* __restrict__ gsum,
    int nbins, int cpg)
{
    int bin = blockIdx.x * 256 + threadIdx.x;
    if (bin >= nbins) return;
    const int g = blockIdx.y;
    int run = 0;
    #pragma unroll 10
    for (int b = g * cpg; b < (g + 1) * cpg; ++b) {
        size_t idx = (size_t)b * nbins + bin;
        int v = part[idx];
        part[idx] = (unsigned short)run;
        run += v;
    }
    gsum[(size_t)g * nbins + bin] = run;
}

// ---------------------------------------------------------------------------
// K5b: exclusive scan over the NGRP group sums (level 2); emits tot.
// ---------------------------------------------------------------------------
__global__ __launch_bounds__(256) void k_tot_fin(
    int* __restrict__ gsum, int* __restrict__ tot, int nbins)
{
    int bin = blockIdx.x * 256 + threadIdx.x;
    if (bin >= nbins) return;
    int run = 0;
    #pragma unroll
    for (int g = 0; g < NGRP; ++g) {
        size_t idx = (size_t)g * nbins + bin;
        int v = gsum[idx];
        gsum[idx] = run;
        run += v;
    }
    tot[bin] = run;
}

// ---------------------------------------------------------------------------
// Multi-block scan, phase 1: per-block sums. 256 thr x 16 elems (int4).
// ---------------------------------------------------------------------------
__global__ __launch_bounds__(256) void k_scan_bsum(
    const int* __restrict__ cnt, int* __restrict__ bsum, int n)
{
    __shared__ int red[256];
    const int base = blockIdx.x * SC_PER_BLOCK + threadIdx.x * SCC;
    int s = 0;
    if (base + SCC <= n) {
        const int4* p4 = (const int4*)(cnt + base);
        #pragma unroll
        for (int j = 0; j < SCC / 4; ++j) {
            int4 v = p4[j];
            s += v.x + v.y + v.z + v.w;
        }
    } else {
        for (int i = base; i < n; ++i) s += cnt[i];
    }
    red[threadIdx.x] = s;
    __syncthreads();
    for (int d = 128; d > 0; d >>= 1) {
        if (threadIdx.x < d) red[threadIdx.x] += red[threadIdx.x + d];
        __syncthreads();
    }
    if (threadIdx.x == 0) bsum[blockIdx.x] = red[0];
}

// ---------------------------------------------------------------------------
// Phase 2: exclusive block bases; writes total into off[n].  nb <= 1024.
// ---------------------------------------------------------------------------
__global__ __launch_bounds__(1024) void k_scan_bbase(
    int* __restrict__ bsum, int nb, int* __restrict__ off, int n)
{
    __shared__ int sums[1024];
    const int tid = threadIdx.x;
    sums[tid] = (tid < nb) ? bsum[tid] : 0;
    __syncthreads();
    for (int d = 1; d < 1024; d <<= 1) {
        int mine = sums[tid];
        int other = (tid >= d) ? sums[tid - d] : 0;
        __syncthreads();
        sums[tid] = mine + other;
        __syncthreads();
    }
    if (tid < nb) bsum[tid] = (tid > 0) ? sums[tid - 1] : 0;
    if (tid == 0) off[n] = sums[1023];
}

// ---------------------------------------------------------------------------
// Phase 3: per-block exclusive scan + block base -> off[i].
// ---------------------------------------------------------------------------
__global__ __launch_bounds__(256) void k_scan_out(
    const int* __restrict__ cnt, const int* __restrict__ bsum,
    int* __restrict__ off, int n)
{
    __shared__ int tsum[256];
    const int base = blockIdx.x * SC_PER_BLOCK + threadIdx.x * SCC;
    int vals[SCC];
    int s = 0;
    if (base + SCC <= n) {
        const int4* p4 = (const int4*)(cnt + base);
        #pragma unroll
        for (int j = 0; j < SCC / 4; ++j) {
            int4 v = p4[j];
            vals[4 * j + 0] = v.x; vals[4 * j + 1] = v.y;
            vals[4 * j + 2] = v.z; vals[4 * j + 3] = v.w;
            s += v.x + v.y + v.z + v.w;
        }
    } else {
        #pragma unroll
        for (int j = 0; j < SCC; ++j) {
            int i = base + j;
            vals[j] = (i < n) ? cnt[i] : 0;
            s += vals[j];
        }
    }
    tsum[threadIdx.x] = s;
    __syncthreads();
    for (int d = 1; d < 256; d <<= 1) {
        int mine = tsum[threadIdx.x];
        int other = (threadIdx.x >= d) ? tsum[threadIdx.x - d] : 0;
        __syncthreads();
        tsum[threadIdx.x] = mine + other;
        __syncthreads();
    }
    int run = bsum[blockIdx.x] + ((threadIdx.x > 0) ? tsum[threadIdx.x - 1] : 0);
    #pragma unroll
    for (int j = 0; j < SCC; ++j) {
        int i = base + j;
        if (i < n) { off[i] = run; run += vals[j]; }
    }
}

// ---------------------------------------------------------------------------
// K6: FUSED flat scatter (edge + node), NO atomics, NO LDS.
// pos_e = eoff[e] + gsum_e[i/200000][e] + part_e[i/CHUNK_E][e] + re[i]
// pos_n = noff[v] + gsum_n[i/200000][v] + part_n[i/CHUNK_N][v] + rn[i]
// ---------------------------------------------------------------------------
__global__ __launch_bounds__(256) void k_scatter_both(
    const int* __restrict__ V, const int* __restrict__ E,
    const unsigned short* __restrict__ re, const unsigned short* __restrict__ rn,
    const unsigned short* __restrict__ part_e,
    const unsigned short* __restrict__ part_n,
    const int* __restrict__ gsum_e, const int* __restrict__ gsum_n,
    const int* __restrict__ eoff, const int* __restrict__ noff,
    const float* __restrict__ wexp,
    int2* __restrict__ epairs, int* __restrict__ nedges)
{
    int i = blockIdx.x * 256 + threadIdx.x;
    if (i >= NNZ) return;
    int e = E[i], v = V[i];
    int be = i / CHUNK_E;
    int bn = i / CHUNK_N;
    int g  = i / 200000;            // = be/CPG_E = bn/CPG_N
    int pe = eoff[e] + gsum_e[(size_t)g * N_EDGES + e]
                     + part_e[(size_t)be * N_EDGES + e] + re[i];
    int pn = noff[v] + gsum_n[(size_t)g * N_NODES + v]
                     + part_n[(size_t)bn * N_NODES + v] + rn[i];
    float w = wexp[v];
    epairs[pe] = make_int2(v, __float_as_int(w));
    nedges[pn] = e;
}

// ---------------------------------------------------------------------------
// helper: accumulate 8 dims (8 halves packed in a float4) with weight w
// ---------------------------------------------------------------------------
__device__ __forceinline__ void acc8h(float w, float4 raw, float (&a)[8])
{
    const __half2* h = (const __half2*)&raw;
    #pragma unroll
    for (int t = 0; t < 4; ++t) {
        float2 f = __half22float2(h[t]);
        a[2*t]   = fmaf(w, f.x, a[2*t]);
        a[2*t+1] = fmaf(w, f.y, a[2*t+1]);
    }
}

// ---------------------------------------------------------------------------
// K8: per-edge aggregation. ONE WAVE PER EDGE, FOUR 16-LANE SLOTS.
// ---------------------------------------------------------------------------
__global__ __launch_bounds__(256) void k_edge_agg(
    const int2* __restrict__ epairs, const int* __restrict__ eoff,
    const __half* __restrict__ Xf16, const float* __restrict__ S,
    float* __restrict__ emsg)
{
    const int wave = threadIdx.x >> 6, lane = threadIdx.x & 63;
    const int e = blockIdx.x * 4 + wave;
    if (e >= N_EDGES) return;
    const int beg = eoff[e], end = eoff[e + 1];
    const int slot = lane >> 4;          // 0..3
    const int sl = lane & 15;            // dims 8*sl .. 8*sl+7
    float a[8] = {};
    float dsum = 0.f;
    int j = beg;
    #pragma unroll 2
    for (; j + 3 < end; j += 4) {
        int2 p = epairs[j + slot];
        float w = __int_as_float(p.y);
        float4 r = *(const float4*)(Xf16 + (size_t)p.x * D + sl * 8);
        dsum += w;
        acc8h(w, r, a);
    }
    if (j + slot < end) {
        int2 p = epairs[j + slot];
        float w = __int_as_float(p.y);
        float4 r = *(const float4*)(Xf16 + (size_t)p.x * D + sl * 8);
        dsum += w;
        acc8h(w, r, a);
    }
    #pragma unroll
    for (int k = 0; k < 8; ++k) {
        a[k] += __shfl_xor(a[k], 16, 64);
        a[k] += __shfl_xor(a[k], 32, 64);
    }
    dsum += __shfl_xor(dsum, 16, 64);
    dsum += __shfl_xor(dsum, 32, 64);

    float inv = (end > beg) ? 1.f / dsum : 0.f;
    float y[8];
    #pragma unroll
    for (int k = 0; k < 8; ++k) {
        float t = a[k] * inv;
        y[k] = (t > 0.f) ? t : expm1f(t);
    }
    const size_t rb = (size_t)e * (D + STAR);
    if (slot == 0) {
        *(float4*)(emsg + rb + sl * 8)     = make_float4(y[0], y[1], y[2], y[3]);
        *(float4*)(emsg + rb + sl * 8 + 4) = make_float4(y[4], y[5], y[6], y[7]);
    } else if (slot == 1) {
        float4 s4 = *(const float4*)(S + (size_t)e * STAR + sl * 4);
        *(float4*)(emsg + rb + D + sl * 4) = s4;
    }
}

// ---------------------------------------------------------------------------
// K9: edge GEMM on matrix cores: Y = e_msg @ Wt^T + Wt_b -> fp16.
// ---------------------------------------------------------------------------
__global__ __launch_bounds__(256) void k_edge_gemm(
    const float* __restrict__ A, const __half* __restrict__ Wtf16,
    const float* __restrict__ Wtb, __half* __restrict__ Y16)
{
    __shared__ char smem[64 * 384];   // 24 KB A-tile; head reused for repack
    const int KDIM = D + STAR;        // 192
    const int tid  = threadIdx.x;
    const int w    = tid >> 6;
    const int lane = tid & 63;
    const int bm   = blockIdx.x * 64;
    const int colbase = w * 32;       // 0,32,64,96
    const int r16 = lane & 15;
    const int hi  = lane >> 4;
    const int g8  = hi * 8;

    {
        const int r = tid >> 2;
        int srow = bm + r; if (srow >= N_EDGES) srow = N_EDGES - 1;
        const float4* src = (const float4*)(A + (size_t)srow * KDIM + (tid & 3) * 48);
        float4 f[12];
        #pragma unroll
        for (int j = 0; j < 12; ++j) f[j] = src[j];
        const int swz  = (r & 7) << 4;
        const int base = r * 384 + (tid & 3) * 96;
        #pragma unroll
        for (int j = 0; j < 6; ++j)
            *(half8*)(smem + ((base + j * 16) ^ swz)) = cvt8(f[2*j], f[2*j+1]);
    }

    half8 bf[6][2];
    #pragma unroll
    for (int ks = 0; ks < 6; ++ks)
        #pragma unroll
        for (int n = 0; n < 2; ++n)
            bf[ks][n] = *(const half8*)(Wtf16 + (size_t)(colbase + n*16 + r16) * KDIM
                                        + ks * 32 + g8);

    __syncthreads();

    floatx4 acc[4][2] = {};
    #pragma unroll
    for (int ks = 0; ks < 6; ++ks) {
        half8 a[4];
        #pragma unroll
        for (int m = 0; m < 4; ++m) {
            const int R = m * 16 + r16;
            a[m] = *(const half8*)(smem + ((R*384 + ks*64 + hi*16) ^ ((R&7)<<4)));
        }
        #pragma unroll
        for (int m = 0; m < 4; ++m)
            #pragma unroll
            for (int n = 0; n < 2; ++n)
                acc[m][n] = __builtin_amdgcn_mfma_f32_16x16x32_f16(
                    a[m], bf[ks][n], acc[m][n], 0, 0, 0);
    }

    const int rq = hi * 4;
    __syncthreads();   // A-tile dead

    {
        __half* sh = (__half*)smem;
        #pragma unroll
        for (int n = 0; n < 2; ++n) {
            const int c = colbase + n * 16 + r16;     // 0..127
            const float bv = Wtb[c];
            #pragma unroll
            for (int m = 0; m < 4; ++m)
                #pragma unroll
                for (int q = 0; q < 4; ++q)
                    sh[(m * 16 + rq + q) * 128 + c] =
                        __float2half(acc[m][n][q] + bv);
        }
    }
    __syncthreads();
    {
        const int r   = tid >> 2;
        const int row = bm + r;
        if (row < N_EDGES) {
            const char* src = smem + r * 256 + (tid & 3) * 64;
            __half* dst = Y16 + (size_t)row * D + (tid & 3) * 32;
            #pragma unroll
            for (int j = 0; j < 4; ++j)
                *(half8*)(dst + j * 8) = *(const half8*)(src + j * 16);
        }
    }
}

// ---------------------------------------------------------------------------
// K10: per-node aggregation. ONE WAVE PER NODE, FOUR 16-LANE SLOTS.
// out[v] = elu(mean_j Y[e_j]) + out[v]   (out holds X_init).
// ---------------------------------------------------------------------------
__global__ __launch_bounds__(256) void k_node_agg(
    const int* __restrict__ nedges, const int* __restrict__ noff,
    const __half* __restrict__ Y16, float* __restrict__ out)
{
    const int wave = threadIdx.x >> 6, lane = threadIdx.x & 63;
    const int v = blockIdx.x * 4 + wave;
    if (v >= N_NODES) return;
    const int beg = noff[v], end = noff[v + 1];
    const int slot = lane >> 4;
    const int sl = lane & 15;
    float a[8] = {};
    int j = beg;
    #pragma unroll 2
    for (; j + 3 < end; j += 4) {
        int e0 = nedges[j + slot];
        float4 r = *(const float4*)(Y16 + (size_t)e0 * D + sl * 8);
        acc8h(1.f, r, a);
    }
    if (j + slot < end) {
        int e0 = nedges[j + slot];
        float4 r = *(const float4*)(Y16 + (size_t)e0 * D + sl * 8);
        acc8h(1.f, r, a);
    }
    #pragma unroll
    for (int k = 0; k < 8; ++k) {
        a[k] += __shfl_xor(a[k], 16, 64);
        a[k] += __shfl_xor(a[k], 32, 64);
    }

    if (slot == 0) {
        int cnt = end - beg;
        float invc = 1.f / (float)max(cnt, 1);
        float x[8];
        #pragma unroll
        for (int k = 0; k < 8; ++k) {
            float t = a[k] * invc;
            x[k] = (t > 0.f) ? t : expm1f(t);
        }
        float4* o0 = (float4*)(out + (size_t)v * D + sl * 8);
        float4* o1 = (float4*)(out + (size_t)v * D + sl * 8 + 4);
        float4 c0 = *o0, c1 = *o1;
        *o0 = make_float4(c0.x + x[0], c0.y + x[1], c0.z + x[2], c0.w + x[3]);
        *o1 = make_float4(c1.x + x[4], c1.y + x[5], c1.z + x[6], c1.w + x[7]);
    }
}

// ---------------------------------------------------------------------------
extern "C" void kernel_launch(void* const* d_in, const int* in_sizes, int n_in,
                              void* d_out, int out_size, void* d_ws, size_t ws_size,
                              hipStream_t stream)
{
    const float* X    = (const float*)d_in[0];
    const int*   V    = (const int*)  d_in[1];
    const int*   E    = (const int*)  d_in[2];
    const float* S    = (const float*)d_in[3];
    const float* Wx_w = (const float*)d_in[4];
    const float* Wx_b = (const float*)d_in[5];
    const float* Wv_w = (const float*)d_in[6];
    const float* Wv_b = (const float*)d_in[7];
    const float* a_w  = (const float*)d_in[8];
    const float* Wt_w = (const float*)d_in[9];
    const float* Wt_b = (const float*)d_in[10];
    float* out = (float*)d_out;

    char* p = (char*)d_ws;
    auto take = [&](size_t bytes) -> char* {
        char* r = p;
        p += (bytes + 255) & ~(size_t)255;
        return r;
    };

    __half* Xf16  = (__half*)take((size_t)N_NODES * D * 2);
    float*  wexp  = (float*) take((size_t)N_NODES * 4);
    unsigned short* part_e = (unsigned short*)take((size_t)NBLK_E * N_EDGES * 2);
    unsigned short* part_n = (unsigned short*)take((size_t)NBLK_N * N_NODES * 2);
    int*    gsum_e = (int*)  take((size_t)NGRP * N_EDGES * 4);
    int*    gsum_n = (int*)  take((size_t)NGRP * N_NODES * 4);
    int*    tot_e = (int*)   take((size_t)N_EDGES * 4);
    int*    tot_n = (int*)   take((size_t)N_NODES * 4);
    int*    eoff  = (int*)   take((size_t)(N_EDGES + 1) * 4);
    int*    noff  = (int*)   take((size_t)(N_NODES + 1) * 4);
    int*    bsum_e = (int*)  take((size_t)SC_NBLK(N_EDGES) * 4);
    int*    bsum_n = (int*)  take((size_t)SC_NBLK(N_NODES) * 4);
    unsigned short* re = (unsigned short*)take((size_t)NNZ * 2);
    unsigned short* rn = (unsigned short*)take((size_t)NNZ * 2);
    int2*   epairs = (int2*) take((size_t)NNZ * 8);
    int*    nedges = (int*)  take((size_t)NNZ * 4);
    float*  emsg  = (float*) take((size_t)N_EDGES * (D + STAR) * 4);
    __half* Y16   = (__half*)take((size_t)N_EDGES * D * 2);
    __half* Wf16  = (__half*)take((size_t)256 * D * 2);          // [Wx;Wv] fp16
    __half* Wtf16 = (__half*)take((size_t)D * (D + STAR) * 2);   // Wt fp16

    k_cvt_w<<<56, 256, 0, stream>>>(Wx_w, Wv_w, Wt_w, Wf16, Wtf16);

    k_node_gemm<<<(N_NODES + 63) / 64, 256, 0, stream>>>(
        X, Wf16, Wx_b, Wv_b, a_w, out, Xf16, wexp);

    k_part_e<<<NBLK_E, 256, 0, stream>>>(E, part_e, re);
    k_part_n<<<dim3(NBLK_N, NPASS_N), 256, 0, stream>>>(V, part_n, rn);

    // two-level chunk scans (8 groups each)
    k_tot_grp<<<dim3((N_EDGES + 255) / 256, NGRP), 256, 0, stream>>>(
        part_e, gsum_e, N_EDGES, CPG_E);
    k_tot_grp<<<dim3((N_NODES + 255) / 256, NGRP), 256, 0, stream>>>(
        part_n, gsum_n, N_NODES, CPG_N);
    k_tot_fin<<<(N_EDGES + 255) / 256, 256, 0, stream>>>(gsum_e, tot_e, N_EDGES);
    k_tot_fin<<<(N_NODES + 255) / 256, 256, 0, stream>>>(gsum_n, tot_n, N_NODES);

    // edge scan (n = 20000, 5 blocks)
    k_scan_bsum<<<SC_NBLK(N_EDGES), 256, 0, stream>>>(tot_e, bsum_e, N_EDGES);
    k_scan_bbase<<<1, 1024, 0, stream>>>(bsum_e, SC_NBLK(N_EDGES), eoff, N_EDGES);
    k_scan_out<<<SC_NBLK(N_EDGES), 256, 0, stream>>>(tot_e, bsum_e, eoff, N_EDGES);

    // node scan (n = 100000, 25 blocks)
    k_scan_bsum<<<SC_NBLK(N_NODES), 256, 0, stream>>>(tot_n, bsum_n, N_NODES);
    k_scan_bbase<<<1, 1024, 0, stream>>>(bsum_n, SC_NBLK(N_NODES), noff, N_NODES);
    k_scan_out<<<SC_NBLK(N_NODES), 256, 0, stream>>>(tot_n, bsum_n, noff, N_NODES);

    k_scatter_both<<<(NNZ + 255) / 256, 256, 0, stream>>>(
        V, E, re, rn, part_e, part_n, gsum_e, gsum_n,
        eoff, noff, wexp, epairs, nedges);

    k_edge_agg<<<(N_EDGES + 3) / 4, 256, 0, stream>>>(epairs, eoff, Xf16, S, emsg);

    k_edge_gemm<<<(N_EDGES + 63) / 64, 256, 0, stream>>>(emsg, Wtf16, Wt_b, Y16);

    k_node_agg<<<(N_NODES + 3) / 4, 256, 0, stream>>>(nedges, noff, Y16, out);
}

// Round 9
// 447.620 us; speedup vs baseline: 1.3447x; 1.0326x over previous
//
#include <hip/hip_runtime.h>
#include <hip/hip_bf16.h>
#include <hip/hip_fp16.h>

#define N_NODES 100000
#define N_EDGES 20000
#define NNZ     1600000
#define D       128
#define STAR    64
#define NEG_SLOPE 0.2f

// edge counting-sort: SINGLE pass, 20000 bins packed as 2xushort per int (40 KB).
#define NBLK_E  400
#define CHUNK_E 4000        // NNZ / NBLK_E
#define H32_E   10000       // ints = 20000 packed ushort bins

// node counting-sort: 5 passes of 20000 packed-ushort bins (40 KB LDS).
#define NBLK_N  64
#define CHUNK_N 25000       // NNZ / NBLK_N
#define BINS_N  20000
#define H32_N   10000
#define NPASS_N 5

// two-level chunk scan: 8 groups for both partitions
#define NGRP    8
#define CPG_E   (NBLK_E / NGRP)   // 50 chunks per group
#define CPG_N   (NBLK_N / NGRP)   // 8 chunks per group
// incidences per group = CPG_E*CHUNK_E = CPG_N*CHUNK_N = 200000 for both

// multi-block scan: 256 threads x 16 elements
#define SCC 16
#define SC_PER_BLOCK (256 * SCC)   // 4096
#define SC_NBLK(n) (((n) + SC_PER_BLOCK - 1) / SC_PER_BLOCK)

typedef _Float16 half8 __attribute__((ext_vector_type(8)));
typedef float    floatx4 __attribute__((ext_vector_type(4)));

// pack 8 fp32 (two float4) -> half8 fragment
__device__ __forceinline__ half8 cvt8(float4 f0, float4 f1)
{
    half8 h;
    h[0] = (_Float16)f0.x; h[1] = (_Float16)f0.y;
    h[2] = (_Float16)f0.z; h[3] = (_Float16)f0.w;
    h[4] = (_Float16)f1.x; h[5] = (_Float16)f1.y;
    h[6] = (_Float16)f1.z; h[7] = (_Float16)f1.w;
    return h;
}

// ---------------------------------------------------------------------------
// K0: one-time fp32 -> fp16 weight conversion.
// ---------------------------------------------------------------------------
__global__ __launch_bounds__(256) void k_cvt_w(
    const float* __restrict__ Wx, const float* __restrict__ Wv,
    const float* __restrict__ Wt,
    __half* __restrict__ Wf16, __half* __restrict__ Wtf16)
{
    int i = (blockIdx.x * 256 + threadIdx.x) * 4;
    const float* src;
    __half* dst;
    if (i < 16384)            { src = Wx + i;         dst = Wf16 + i; }
    else if (i < 32768)       { src = Wv + (i-16384); dst = Wf16 + i; }
    else if (i < 32768+24576) { src = Wt + (i-32768); dst = Wtf16 + (i-32768); }
    else return;
    float4 f = *(const float4*)src;
    *(__half2*)(dst)     = __floats2half2_rn(f.x, f.y);
    *(__half2*)(dst + 2) = __floats2half2_rn(f.z, f.w);
}

// ---------------------------------------------------------------------------
// K1: fused node GEMM on matrix cores + FUSED SCORE.
//   [X_init | X_feat] = X @ [Wx^T | Wv^T] + bias;  wexp = exp(lrelu(Xf.a))
// ---------------------------------------------------------------------------
__global__ __launch_bounds__(256) void k_node_gemm(
    const float* __restrict__ X, const __half* __restrict__ Wf16,
    const float* __restrict__ Wxb, const float* __restrict__ Wvb,
    const float* __restrict__ aw,
    float* __restrict__ Xinit, __half* __restrict__ Xf16,
    float* __restrict__ wexp)
{
    __shared__ char smem[64 * 256];   // 16 KB A-tile; reused for fp16 repack
    const int tid  = threadIdx.x;
    const int w    = tid >> 6;
    const int lane = tid & 63;
    const int bm   = blockIdx.x * 64;
    const int colbase = w * 64;               // 0,64,128,192
    const bool isInit = (colbase < D);
    const int r16 = lane & 15;
    const int hi  = lane >> 4;                // 0..3
    const int g8  = hi * 8;

    // ---- stage A tile: coalesced fp32 load -> fp16 -> swizzled LDS ----
    {
        const int r  = tid >> 2;              // 0..63
        int srow = bm + r; if (srow >= N_NODES) srow = N_NODES - 1;
        const float4* src = (const float4*)(X + (size_t)srow * D + (tid & 3) * 32);
        float4 f[8];
        #pragma unroll
        for (int j = 0; j < 8; ++j) f[j] = src[j];
        const int swz  = (r & 7) << 4;
        const int base = r * 256 + (tid & 3) * 64;
        #pragma unroll
        for (int j = 0; j < 4; ++j)
            *(half8*)(smem + ((base + j * 16) ^ swz)) = cvt8(f[2*j], f[2*j+1]);
    }

    // ---- hoist all 16 B fragments (fp16, L2-resident) ----
    half8 bf[4][4];
    #pragma unroll
    for (int ks = 0; ks < 4; ++ks)
        #pragma unroll
        for (int n = 0; n < 4; ++n)
            bf[ks][n] = *(const half8*)(Wf16 + (size_t)(colbase + n*16 + r16) * D
                                        + ks * 32 + g8);

    __syncthreads();

    floatx4 acc[4][4] = {};
    #pragma unroll
    for (int ks = 0; ks < 4; ++ks) {
        half8 a[4];
        #pragma unroll
        for (int m = 0; m < 4; ++m) {
            const int R = m * 16 + r16;
            a[m] = *(const half8*)(smem + ((R*256 + ks*64 + hi*16) ^ ((R&7)<<4)));
        }
        #pragma unroll
        for (int m = 0; m < 4; ++m)
            #pragma unroll
            for (int n = 0; n < 4; ++n)
                acc[m][n] = __builtin_amdgcn_mfma_f32_16x16x32_f16(
                    a[m], bf[ks][n], acc[m][n], 0, 0, 0);
    }

    const float* bias = isInit ? Wxb : Wvb;
    const int rq = hi * 4;

    __syncthreads();   // A-tile dead; smem reusable

    if (isInit) {
        #pragma unroll
        for (int n = 0; n < 4; ++n) {
            const int c = (colbase & (D - 1)) + n * 16 + r16;
            const float bv = bias[c];
            #pragma unroll
            for (int m = 0; m < 4; ++m)
                #pragma unroll
                for (int q = 0; q < 4; ++q) {
                    const int row = bm + m * 16 + rq + q;
                    if (row < N_NODES)
                        Xinit[(size_t)row * D + c] = acc[m][n][q] + bv;
                }
        }
    } else {
        __half* sh = (__half*)smem;
        #pragma unroll
        for (int n = 0; n < 4; ++n) {
            const int lc = (colbase - D) + n * 16 + r16;   // 0..127
            const float bv = bias[(colbase & (D - 1)) + n * 16 + r16];
            #pragma unroll
            for (int m = 0; m < 4; ++m)
                #pragma unroll
                for (int q = 0; q < 4; ++q)
                    sh[(m * 16 + rq + q) * 128 + lc] =
                        __float2half(acc[m][n][q] + bv);
        }
    }
    __syncthreads();
    // coalesced Xf16 store + fused score (4 threads per row)
    {
        const int r   = tid >> 2;
        const int row = bm + r;
        const int q4  = tid & 3;
        if (row < N_NODES) {
            const char* src = smem + r * 256 + q4 * 64;
            __half* dst = Xf16 + (size_t)row * D + q4 * 32;
            float part = 0.f;
            #pragma unroll
            for (int j = 0; j < 4; ++j) {
                half8 h = *(const half8*)(src + j * 16);
                *(half8*)(dst + j * 8) = h;
                float4 a0 = *(const float4*)(aw + q4 * 32 + j * 8);
                float4 a1 = *(const float4*)(aw + q4 * 32 + j * 8 + 4);
                part += (float)h[0]*a0.x + (float)h[1]*a0.y
                      + (float)h[2]*a0.z + (float)h[3]*a0.w
                      + (float)h[4]*a1.x + (float)h[5]*a1.y
                      + (float)h[6]*a1.z + (float)h[7]*a1.w;
            }
            part += __shfl_xor(part, 1, 64);
            part += __shfl_xor(part, 2, 64);
            if (q4 == 0) {
                float l = (part > 0.f) ? part : NEG_SLOPE * part;
                wexp[row] = expf(l);
            }
        }
    }
}

// ---------------------------------------------------------------------------
// K3: edge histogram+rank, SINGLE pass, packed 2xushort-per-int LDS bins.
// ---------------------------------------------------------------------------
__global__ __launch_bounds__(256) void k_part_e(
    const int* __restrict__ E, unsigned short* __restrict__ part,
    unsigned short* __restrict__ re)
{
    __shared__ int h[H32_E];
    const int b = blockIdx.x;
    const int i0 = b * CHUNK_E;
    for (int t = threadIdx.x; t < H32_E; t += 256) h[t] = 0;
    __syncthreads();
    const int4* E4 = (const int4*)(E + i0);
    for (int i = threadIdx.x; i < CHUNK_E / 4; i += 256) {
        int4 q = E4[i];
        int ev[4] = {q.x, q.y, q.z, q.w};
        #pragma unroll
        for (int t = 0; t < 4; ++t) {
            int e = ev[t];
            unsigned sh = (e & 1) << 4;
            int old = atomicAdd(&h[e >> 1], 1 << sh);
            re[i0 + i * 4 + t] = (unsigned short)((unsigned)old >> sh);
        }
    }
    __syncthreads();
    int* dst = (int*)(part + (size_t)b * N_EDGES);
    for (int t = threadIdx.x; t < H32_E; t += 256) dst[t] = h[t];
}

// ---------------------------------------------------------------------------
// K3b: node histogram+rank, 5 passes x 20000 packed bins (40 KB LDS).
// ---------------------------------------------------------------------------
__global__ __launch_bounds__(256) void k_part_n(
    const int* __restrict__ V, unsigned short* __restrict__ part,
    unsigned short* __restrict__ rn)
{
    __shared__ int h[H32_N];
    const int b = blockIdx.x;
    const int c0 = blockIdx.y * BINS_N;
    const int i0 = b * CHUNK_N;
    for (int t = threadIdx.x; t < H32_N; t += 256) h[t] = 0;
    __syncthreads();
    const int4* V4 = (const int4*)(V + i0);
    for (int i = threadIdx.x; i < CHUNK_N / 4; i += 256) {
        int4 q = V4[i];
        int vv[4] = {q.x, q.y, q.z, q.w};
        #pragma unroll
        for (int t = 0; t < 4; ++t) {
            int c = vv[t] - c0;
            if ((unsigned)c < (unsigned)BINS_N) {
                unsigned sh = (c & 1) << 4;
                int old = atomicAdd(&h[c >> 1], 1 << sh);
                rn[i0 + i * 4 + t] = (unsigned short)((unsigned)old >> sh);
            }
        }
    }
    __syncthreads();
    int* dst = (int*)(part + (size_t)b * N_NODES + c0);
    for (int t = threadIdx.x; t < H32_N; t += 256) dst[t] = h[t];
}

// ---------------------------------------------------------------------------
// K5a: within-GROUP exclusive scan over chunks (level 1 of 2).
// ---------------------------------------------------------------------------
__global__ __launch_bounds__(256) void k_tot_grp(
    unsigned short* __restrict__ part, int* __restrict__ gsum,
    int nbins, int cpg)
{
    int bin = blockIdx.x * 256 + threadIdx.x;
    if (bin >= nbins) return;
    const int g = blockIdx.y;
    int run = 0;
    #pragma unroll 10
    for (int b = g * cpg; b < (g + 1) * cpg; ++b) {
        size_t idx = (size_t)b * nbins + bin;
        int v = part[idx];
        part[idx] = (unsigned short)run;
        run += v;
    }
    gsum[(size_t)g * nbins + bin] = run;
}

// ---------------------------------------------------------------------------
// K5b: exclusive scan over the NGRP group sums (level 2); emits tot.
// ---------------------------------------------------------------------------
__global__ __launch_bounds__(256) void k_tot_fin(
    int* __restrict__ gsum, int* __restrict__ tot, int nbins)
{
    int bin = blockIdx.x * 256 + threadIdx.x;
    if (bin >= nbins) return;
    int run = 0;
    #pragma unroll
    for (int g = 0; g < NGRP; ++g) {
        size_t idx = (size_t)g * nbins + bin;
        int v = gsum[idx];
        gsum[idx] = run;
        run += v;
    }
    tot[bin] = run;
}

// ---------------------------------------------------------------------------
// Multi-block scan, phase 1: per-block sums. 256 thr x 16 elems (int4).
// ---------------------------------------------------------------------------
__global__ __launch_bounds__(256) void k_scan_bsum(
    const int* __restrict__ cnt, int* __restrict__ bsum, int n)
{
    __shared__ int red[256];
    const int base = blockIdx.x * SC_PER_BLOCK + threadIdx.x * SCC;
    int s = 0;
    if (base + SCC <= n) {
        const int4* p4 = (const int4*)(cnt + base);
        #pragma unroll
        for (int j = 0; j < SCC / 4; ++j) {
            int4 v = p4[j];
            s += v.x + v.y + v.z + v.w;
        }
    } else {
        for (int i = base; i < n; ++i) s += cnt[i];
    }
    red[threadIdx.x] = s;
    __syncthreads();
    for (int d = 128; d > 0; d >>= 1) {
        if (threadIdx.x < d) red[threadIdx.x] += red[threadIdx.x + d];
        __syncthreads();
    }
    if (threadIdx.x == 0) bsum[blockIdx.x] = red[0];
}

// ---------------------------------------------------------------------------
// Phase 2: exclusive block bases; writes total into off[n].  nb <= 1024.
// ---------------------------------------------------------------------------
__global__ __launch_bounds__(1024) void k_scan_bbase(
    int* __restrict__ bsum, int nb, int* __restrict__ off, int n)
{
    __shared__ int sums[1024];
    const int tid = threadIdx.x;
    sums[tid] = (tid < nb) ? bsum[tid] : 0;
    __syncthreads();
    for (int d = 1; d < 1024; d <<= 1) {
        int mine = sums[tid];
        int other = (tid >= d) ? sums[tid - d] : 0;
        __syncthreads();
        sums[tid] = mine + other;
        __syncthreads();
    }
    if (tid < nb) bsum[tid] = (tid > 0) ? sums[tid - 1] : 0;
    if (tid == 0) off[n] = sums[1023];
}

// ---------------------------------------------------------------------------
// Phase 3: per-block exclusive scan + block base -> off[i].
// ---------------------------------------------------------------------------
__global__ __launch_bounds__(256) void k_scan_out(
    const int* __restrict__ cnt, const int* __restrict__ bsum,
    int* __restrict__ off, int n)
{
    __shared__ int tsum[256];
    const int base = blockIdx.x * SC_PER_BLOCK + threadIdx.x * SCC;
    int vals[SCC];
    int s = 0;
    if (base + SCC <= n) {
        const int4* p4 = (const int4*)(cnt + base);
        #pragma unroll
        for (int j = 0; j < SCC / 4; ++j) {
            int4 v = p4[j];
            vals[4 * j + 0] = v.x; vals[4 * j + 1] = v.y;
            vals[4 * j + 2] = v.z; vals[4 * j + 3] = v.w;
            s += v.x + v.y + v.z + v.w;
        }
    } else {
        #pragma unroll
        for (int j = 0; j < SCC; ++j) {
            int i = base + j;
            vals[j] = (i < n) ? cnt[i] : 0;
            s += vals[j];
        }
    }
    tsum[threadIdx.x] = s;
    __syncthreads();
    for (int d = 1; d < 256; d <<= 1) {
        int mine = tsum[threadIdx.x];
        int other = (threadIdx.x >= d) ? tsum[threadIdx.x - d] : 0;
        __syncthreads();
        tsum[threadIdx.x] = mine + other;
        __syncthreads();
    }
    int run = bsum[blockIdx.x] + ((threadIdx.x > 0) ? tsum[threadIdx.x - 1] : 0);
    #pragma unroll
    for (int j = 0; j < SCC; ++j) {
        int i = base + j;
        if (i < n) { off[i] = run; run += vals[j]; }
    }
}

// ---------------------------------------------------------------------------
// K6: FUSED flat scatter (edge + node), NO atomics, NO LDS.
// Shrunk payloads: epairs = int (v only; w gathered later from wexp),
// nedges = ushort (e < 20000). Halves scattered-line count -> halves
// RFO + writeback amplification (round-7 counters: 161+103 MB for a
// 25+19 MB payload).
// ---------------------------------------------------------------------------
__global__ __launch_bounds__(256) void k_scatter_both(
    const int* __restrict__ V, const int* __restrict__ E,
    const unsigned short* __restrict__ re, const unsigned short* __restrict__ rn,
    const unsigned short* __restrict__ part_e,
    const unsigned short* __restrict__ part_n,
    const int* __restrict__ gsum_e, const int* __restrict__ gsum_n,
    const int* __restrict__ eoff, const int* __restrict__ noff,
    int* __restrict__ epairs, unsigned short* __restrict__ nedges)
{
    int i = blockIdx.x * 256 + threadIdx.x;
    if (i >= NNZ) return;
    int e = E[i], v = V[i];
    int be = i / CHUNK_E;
    int bn = i / CHUNK_N;
    int g  = i / 200000;            // = be/CPG_E = bn/CPG_N
    int pe = eoff[e] + gsum_e[(size_t)g * N_EDGES + e]
                     + part_e[(size_t)be * N_EDGES + e] + re[i];
    int pn = noff[v] + gsum_n[(size_t)g * N_NODES + v]
                     + part_n[(size_t)bn * N_NODES + v] + rn[i];
    epairs[pe] = v;
    nedges[pn] = (unsigned short)e;
}

// ---------------------------------------------------------------------------
// helper: accumulate 8 dims (8 halves packed in a float4) with weight w
// ---------------------------------------------------------------------------
__device__ __forceinline__ void acc8h(float w, float4 raw, float (&a)[8])
{
    const __half2* h = (const __half2*)&raw;
    #pragma unroll
    for (int t = 0; t < 4; ++t) {
        float2 f = __half22float2(h[t]);
        a[2*t]   = fmaf(w, f.x, a[2*t]);
        a[2*t+1] = fmaf(w, f.y, a[2*t+1]);
    }
}

// ---------------------------------------------------------------------------
// K8: per-edge aggregation. ONE WAVE PER EDGE, FOUR 16-LANE SLOTS.
// w gathered from the 400 KB L2-resident wexp table (epairs is v-only now).
// ---------------------------------------------------------------------------
__global__ __launch_bounds__(256) void k_edge_agg(
    const int* __restrict__ epairs, const int* __restrict__ eoff,
    const float* __restrict__ wexp,
    const __half* __restrict__ Xf16, const float* __restrict__ S,
    float* __restrict__ emsg)
{
    const int wave = threadIdx.x >> 6, lane = threadIdx.x & 63;
    const int e = blockIdx.x * 4 + wave;
    if (e >= N_EDGES) return;
    const int beg = eoff[e], end = eoff[e + 1];
    const int slot = lane >> 4;          // 0..3
    const int sl = lane & 15;            // dims 8*sl .. 8*sl+7
    float a[8] = {};
    float dsum = 0.f;
    int j = beg;
    #pragma unroll 2
    for (; j + 3 < end; j += 4) {
        int v = epairs[j + slot];
        float w = wexp[v];
        float4 r = *(const float4*)(Xf16 + (size_t)v * D + sl * 8);
        dsum += w;
        acc8h(w, r, a);
    }
    if (j + slot < end) {
        int v = epairs[j + slot];
        float w = wexp[v];
        float4 r = *(const float4*)(Xf16 + (size_t)v * D + sl * 8);
        dsum += w;
        acc8h(w, r, a);
    }
    #pragma unroll
    for (int k = 0; k < 8; ++k) {
        a[k] += __shfl_xor(a[k], 16, 64);
        a[k] += __shfl_xor(a[k], 32, 64);
    }
    dsum += __shfl_xor(dsum, 16, 64);
    dsum += __shfl_xor(dsum, 32, 64);

    float inv = (end > beg) ? 1.f / dsum : 0.f;
    float y[8];
    #pragma unroll
    for (int k = 0; k < 8; ++k) {
        float t = a[k] * inv;
        y[k] = (t > 0.f) ? t : expm1f(t);
    }
    const size_t rb = (size_t)e * (D + STAR);
    if (slot == 0) {
        *(float4*)(emsg + rb + sl * 8)     = make_float4(y[0], y[1], y[2], y[3]);
        *(float4*)(emsg + rb + sl * 8 + 4) = make_float4(y[4], y[5], y[6], y[7]);
    } else if (slot == 1) {
        float4 s4 = *(const float4*)(S + (size_t)e * STAR + sl * 4);
        *(float4*)(emsg + rb + D + sl * 4) = s4;
    }
}

// ---------------------------------------------------------------------------
// K9: edge GEMM on matrix cores: Y = e_msg @ Wt^T + Wt_b -> fp16.
// ---------------------------------------------------------------------------
__global__ __launch_bounds__(256) void k_edge_gemm(
    const float* __restrict__ A, const __half* __restrict__ Wtf16,
    const float* __restrict__ Wtb, __half* __restrict__ Y16)
{
    __shared__ char smem[64 * 384];   // 24 KB A-tile; head reused for repack
    const int KDIM = D + STAR;        // 192
    const int tid  = threadIdx.x;
    const int w    = tid >> 6;
    const int lane = tid & 63;
    const int bm   = blockIdx.x * 64;
    const int colbase = w * 32;       // 0,32,64,96
    const int r16 = lane & 15;
    const int hi  = lane >> 4;
    const int g8  = hi * 8;

    {
        const int r = tid >> 2;
        int srow = bm + r; if (srow >= N_EDGES) srow = N_EDGES - 1;
        const float4* src = (const float4*)(A + (size_t)srow * KDIM + (tid & 3) * 48);
        float4 f[12];
        #pragma unroll
        for (int j = 0; j < 12; ++j) f[j] = src[j];
        const int swz  = (r & 7) << 4;
        const int base = r * 384 + (tid & 3) * 96;
        #pragma unroll
        for (int j = 0; j < 6; ++j)
            *(half8*)(smem + ((base + j * 16) ^ swz)) = cvt8(f[2*j], f[2*j+1]);
    }

    half8 bf[6][2];
    #pragma unroll
    for (int ks = 0; ks < 6; ++ks)
        #pragma unroll
        for (int n = 0; n < 2; ++n)
            bf[ks][n] = *(const half8*)(Wtf16 + (size_t)(colbase + n*16 + r16) * KDIM
                                        + ks * 32 + g8);

    __syncthreads();

    floatx4 acc[4][2] = {};
    #pragma unroll
    for (int ks = 0; ks < 6; ++ks) {
        half8 a[4];
        #pragma unroll
        for (int m = 0; m < 4; ++m) {
            const int R = m * 16 + r16;
            a[m] = *(const half8*)(smem + ((R*384 + ks*64 + hi*16) ^ ((R&7)<<4)));
        }
        #pragma unroll
        for (int m = 0; m < 4; ++m)
            #pragma unroll
            for (int n = 0; n < 2; ++n)
                acc[m][n] = __builtin_amdgcn_mfma_f32_16x16x32_f16(
                    a[m], bf[ks][n], acc[m][n], 0, 0, 0);
    }

    const int rq = hi * 4;
    __syncthreads();   // A-tile dead

    {
        __half* sh = (__half*)smem;
        #pragma unroll
        for (int n = 0; n < 2; ++n) {
            const int c = colbase + n * 16 + r16;     // 0..127
            const float bv = Wtb[c];
            #pragma unroll
            for (int m = 0; m < 4; ++m)
                #pragma unroll
                for (int q = 0; q < 4; ++q)
                    sh[(m * 16 + rq + q) * 128 + c] =
                        __float2half(acc[m][n][q] + bv);
        }
    }
    __syncthreads();
    {
        const int r   = tid >> 2;
        const int row = bm + r;
        if (row < N_EDGES) {
            const char* src = smem + r * 256 + (tid & 3) * 64;
            __half* dst = Y16 + (size_t)row * D + (tid & 3) * 32;
            #pragma unroll
            for (int j = 0; j < 4; ++j)
                *(half8*)(dst + j * 8) = *(const half8*)(src + j * 16);
        }
    }
}

// ---------------------------------------------------------------------------
// K10: per-node aggregation. ONE WAVE PER NODE, FOUR 16-LANE SLOTS.
// nedges is ushort now (e < 20000).
// out[v] = elu(mean_j Y[e_j]) + out[v]   (out holds X_init).
// ---------------------------------------------------------------------------
__global__ __launch_bounds__(256) void k_node_agg(
    const unsigned short* __restrict__ nedges, const int* __restrict__ noff,
    const __half* __restrict__ Y16, float* __restrict__ out)
{
    const int wave = threadIdx.x >> 6, lane = threadIdx.x & 63;
    const int v = blockIdx.x * 4 + wave;
    if (v >= N_NODES) return;
    const int beg = noff[v], end = noff[v + 1];
    const int slot = lane >> 4;
    const int sl = lane & 15;
    float a[8] = {};
    int j = beg;
    #pragma unroll 2
    for (; j + 3 < end; j += 4) {
        int e0 = nedges[j + slot];
        float4 r = *(const float4*)(Y16 + (size_t)e0 * D + sl * 8);
        acc8h(1.f, r, a);
    }
    if (j + slot < end) {
        int e0 = nedges[j + slot];
        float4 r = *(const float4*)(Y16 + (size_t)e0 * D + sl * 8);
        acc8h(1.f, r, a);
    }
    #pragma unroll
    for (int k = 0; k < 8; ++k) {
        a[k] += __shfl_xor(a[k], 16, 64);
        a[k] += __shfl_xor(a[k], 32, 64);
    }

    if (slot == 0) {
        int cnt = end - beg;
        float invc = 1.f / (float)max(cnt, 1);
        float x[8];
        #pragma unroll
        for (int k = 0; k < 8; ++k) {
            float t = a[k] * invc;
            x[k] = (t > 0.f) ? t : expm1f(t);
        }
        float4* o0 = (float4*)(out + (size_t)v * D + sl * 8);
        float4* o1 = (float4*)(out + (size_t)v * D + sl * 8 + 4);
        float4 c0 = *o0, c1 = *o1;
        *o0 = make_float4(c0.x + x[0], c0.y + x[1], c0.z + x[2], c0.w + x[3]);
        *o1 = make_float4(c1.x + x[4], c1.y + x[5], c1.z + x[6], c1.w + x[7]);
    }
}

// ---------------------------------------------------------------------------
extern "C" void kernel_launch(void* const* d_in, const int* in_sizes, int n_in,
                              void* d_out, int out_size, void* d_ws, size_t ws_size,
                              hipStream_t stream)
{
    const float* X    = (const float*)d_in[0];
    const int*   V    = (const int*)  d_in[1];
    const int*   E    = (const int*)  d_in[2];
    const float* S    = (const float*)d_in[3];
    const float* Wx_w = (const float*)d_in[4];
    const float* Wx_b = (const float*)d_in[5];
    const float* Wv_w = (const float*)d_in[6];
    const float* Wv_b = (const float*)d_in[7];
    const float* a_w  = (const float*)d_in[8];
    const float* Wt_w = (const float*)d_in[9];
    const float* Wt_b = (const float*)d_in[10];
    float* out = (float*)d_out;

    char* p = (char*)d_ws;
    auto take = [&](size_t bytes) -> char* {
        char* r = p;
        p += (bytes + 255) & ~(size_t)255;
        return r;
    };

    __half* Xf16  = (__half*)take((size_t)N_NODES * D * 2);
    float*  wexp  = (float*) take((size_t)N_NODES * 4);
    unsigned short* part_e = (unsigned short*)take((size_t)NBLK_E * N_EDGES * 2);
    unsigned short* part_n = (unsigned short*)take((size_t)NBLK_N * N_NODES * 2);
    int*    gsum_e = (int*)  take((size_t)NGRP * N_EDGES * 4);
    int*    gsum_n = (int*)  take((size_t)NGRP * N_NODES * 4);
    int*    tot_e = (int*)   take((size_t)N_EDGES * 4);
    int*    tot_n = (int*)   take((size_t)N_NODES * 4);
    int*    eoff  = (int*)   take((size_t)(N_EDGES + 1) * 4);
    int*    noff  = (int*)   take((size_t)(N_NODES + 1) * 4);
    int*    bsum_e = (int*)  take((size_t)SC_NBLK(N_EDGES) * 4);
    int*    bsum_n = (int*)  take((size_t)SC_NBLK(N_NODES) * 4);
    unsigned short* re = (unsigned short*)take((size_t)NNZ * 2);
    unsigned short* rn = (unsigned short*)take((size_t)NNZ * 2);
    int*    epairs = (int*)  take((size_t)NNZ * 4);
    unsigned short* nedges = (unsigned short*)take((size_t)NNZ * 2);
    float*  emsg  = (float*) take((size_t)N_EDGES * (D + STAR) * 4);
    __half* Y16   = (__half*)take((size_t)N_EDGES * D * 2);
    __half* Wf16  = (__half*)take((size_t)256 * D * 2);          // [Wx;Wv] fp16
    __half* Wtf16 = (__half*)take((size_t)D * (D + STAR) * 2);   // Wt fp16

    k_cvt_w<<<56, 256, 0, stream>>>(Wx_w, Wv_w, Wt_w, Wf16, Wtf16);

    k_node_gemm<<<(N_NODES + 63) / 64, 256, 0, stream>>>(
        X, Wf16, Wx_b, Wv_b, a_w, out, Xf16, wexp);

    k_part_e<<<NBLK_E, 256, 0, stream>>>(E, part_e, re);
    k_part_n<<<dim3(NBLK_N, NPASS_N), 256, 0, stream>>>(V, part_n, rn);

    // two-level chunk scans (8 groups each)
    k_tot_grp<<<dim3((N_EDGES + 255) / 256, NGRP), 256, 0, stream>>>(
        part_e, gsum_e, N_EDGES, CPG_E);
    k_tot_grp<<<dim3((N_NODES + 255) / 256, NGRP), 256, 0, stream>>>(
        part_n, gsum_n, N_NODES, CPG_N);
    k_tot_fin<<<(N_EDGES + 255) / 256, 256, 0, stream>>>(gsum_e, tot_e, N_EDGES);
    k_tot_fin<<<(N_NODES + 255) / 256, 256, 0, stream>>>(gsum_n, tot_n, N_NODES);

    // edge scan (n = 20000, 5 blocks)
    k_scan_bsum<<<SC_NBLK(N_EDGES), 256, 0, stream>>>(tot_e, bsum_e, N_EDGES);
    k_scan_bbase<<<1, 1024, 0, stream>>>(bsum_e, SC_NBLK(N_EDGES), eoff, N_EDGES);
    k_scan_out<<<SC_NBLK(N_EDGES), 256, 0, stream>>>(tot_e, bsum_e, eoff, N_EDGES);

    // node scan (n = 100000, 25 blocks)
    k_scan_bsum<<<SC_NBLK(N_NODES), 256, 0, stream>>>(tot_n, bsum_n, N_NODES);
    k_scan_bbase<<<1, 1024, 0, stream>>>(bsum_n, SC_NBLK(N_NODES), noff, N_NODES);
    k_scan_out<<<SC_NBLK(N_NODES), 256, 0, stream>>>(tot_n, bsum_n, noff, N_NODES);

    k_scatter_both<<<(NNZ + 255) / 256, 256, 0, stream>>>(
        V, E, re, rn, part_e, part_n, gsum_e, gsum_n,
        eoff, noff, epairs, nedges);

    k_edge_agg<<<(N_EDGES + 3) / 4, 256, 0, stream>>>(
        epairs, eoff, wexp, Xf16, S, emsg);

    k_edge_gemm<<<(N_EDGES + 63) / 64, 256, 0, stream>>>(emsg, Wtf16, Wt_b, Y16);

    k_node_agg<<<(N_NODES + 3) / 4, 256, 0, stream>>>(nedges, noff, Y16, out);
}

// Round 10
// 426.955 us; speedup vs baseline: 1.4098x; 1.0484x over previous
//
#include <hip/hip_runtime.h>
#include <hip/hip_bf16.h>
#include <hip/hip_fp16.h>

#define N_NODES 100000
#define N_EDGES 20000
#define NNZ     1600000
#define D       128
#define STAR    64
#define NEG_SLOPE 0.2f

// edge counting-sort: SINGLE pass, 20000 bins packed as 2xushort per int (40 KB).
#define NBLK_E  400
#define CHUNK_E 4000        // NNZ / NBLK_E
#define H32_E   10000       // ints = 20000 packed ushort bins

// node counting-sort: 5 passes of 20000 packed-ushort bins (40 KB LDS).
#define NBLK_N  64
#define CHUNK_N 25000       // NNZ / NBLK_N
#define BINS_N  20000
#define H32_N   10000
#define NPASS_N 5

// two-level chunk scan: 8 groups for both partitions (== 8 XCDs)
#define NGRP    8
#define CPG_E   (NBLK_E / NGRP)   // 50 chunks per group
#define CPG_N   (NBLK_N / NGRP)   // 8 chunks per group
// incidences per group = CPG_E*CHUNK_E = CPG_N*CHUNK_N = 200000 for both

// scatter grid geometry for XCD-chunked remap
#define SCAT_NWG ((NNZ + 255) / 256)   // 6250
#define SCAT_Q   (SCAT_NWG / 8)        // 781
#define SCAT_R   (SCAT_NWG % 8)        // 2

// multi-block scan: 256 threads x 16 elements
#define SCC 16
#define SC_PER_BLOCK (256 * SCC)   // 4096
#define SC_NBLK(n) (((n) + SC_PER_BLOCK - 1) / SC_PER_BLOCK)

typedef _Float16 half8 __attribute__((ext_vector_type(8)));
typedef float    floatx4 __attribute__((ext_vector_type(4)));

// pack 8 fp32 (two float4) -> half8 fragment
__device__ __forceinline__ half8 cvt8(float4 f0, float4 f1)
{
    half8 h;
    h[0] = (_Float16)f0.x; h[1] = (_Float16)f0.y;
    h[2] = (_Float16)f0.z; h[3] = (_Float16)f0.w;
    h[4] = (_Float16)f1.x; h[5] = (_Float16)f1.y;
    h[6] = (_Float16)f1.z; h[7] = (_Float16)f1.w;
    return h;
}

// ---------------------------------------------------------------------------
// K0: one-time fp32 -> fp16 weight conversion.
// ---------------------------------------------------------------------------
__global__ __launch_bounds__(256) void k_cvt_w(
    const float* __restrict__ Wx, const float* __restrict__ Wv,
    const float* __restrict__ Wt,
    __half* __restrict__ Wf16, __half* __restrict__ Wtf16)
{
    int i = (blockIdx.x * 256 + threadIdx.x) * 4;
    const float* src;
    __half* dst;
    if (i < 16384)            { src = Wx + i;         dst = Wf16 + i; }
    else if (i < 32768)       { src = Wv + (i-16384); dst = Wf16 + i; }
    else if (i < 32768+24576) { src = Wt + (i-32768); dst = Wtf16 + (i-32768); }
    else return;
    float4 f = *(const float4*)src;
    *(__half2*)(dst)     = __floats2half2_rn(f.x, f.y);
    *(__half2*)(dst + 2) = __floats2half2_rn(f.z, f.w);
}

// ---------------------------------------------------------------------------
// K1: fused node GEMM on matrix cores + FUSED SCORE.
//   [X_init | X_feat] = X @ [Wx^T | Wv^T] + bias;  wexp = exp(lrelu(Xf.a))
// ---------------------------------------------------------------------------
__global__ __launch_bounds__(256) void k_node_gemm(
    const float* __restrict__ X, const __half* __restrict__ Wf16,
    const float* __restrict__ Wxb, const float* __restrict__ Wvb,
    const float* __restrict__ aw,
    float* __restrict__ Xinit, __half* __restrict__ Xf16,
    float* __restrict__ wexp)
{
    __shared__ char smem[64 * 256];   // 16 KB A-tile; reused for fp16 repack
    const int tid  = threadIdx.x;
    const int w    = tid >> 6;
    const int lane = tid & 63;
    const int bm   = blockIdx.x * 64;
    const int colbase = w * 64;               // 0,64,128,192
    const bool isInit = (colbase < D);
    const int r16 = lane & 15;
    const int hi  = lane >> 4;                // 0..3
    const int g8  = hi * 8;

    // ---- stage A tile: coalesced fp32 load -> fp16 -> swizzled LDS ----
    {
        const int r  = tid >> 2;              // 0..63
        int srow = bm + r; if (srow >= N_NODES) srow = N_NODES - 1;
        const float4* src = (const float4*)(X + (size_t)srow * D + (tid & 3) * 32);
        float4 f[8];
        #pragma unroll
        for (int j = 0; j < 8; ++j) f[j] = src[j];
        const int swz  = (r & 7) << 4;
        const int base = r * 256 + (tid & 3) * 64;
        #pragma unroll
        for (int j = 0; j < 4; ++j)
            *(half8*)(smem + ((base + j * 16) ^ swz)) = cvt8(f[2*j], f[2*j+1]);
    }

    // ---- hoist all 16 B fragments (fp16, L2-resident) ----
    half8 bf[4][4];
    #pragma unroll
    for (int ks = 0; ks < 4; ++ks)
        #pragma unroll
        for (int n = 0; n < 4; ++n)
            bf[ks][n] = *(const half8*)(Wf16 + (size_t)(colbase + n*16 + r16) * D
                                        + ks * 32 + g8);

    __syncthreads();

    floatx4 acc[4][4] = {};
    #pragma unroll
    for (int ks = 0; ks < 4; ++ks) {
        half8 a[4];
        #pragma unroll
        for (int m = 0; m < 4; ++m) {
            const int R = m * 16 + r16;
            a[m] = *(const half8*)(smem + ((R*256 + ks*64 + hi*16) ^ ((R&7)<<4)));
        }
        #pragma unroll
        for (int m = 0; m < 4; ++m)
            #pragma unroll
            for (int n = 0; n < 4; ++n)
                acc[m][n] = __builtin_amdgcn_mfma_f32_16x16x32_f16(
                    a[m], bf[ks][n], acc[m][n], 0, 0, 0);
    }

    const float* bias = isInit ? Wxb : Wvb;
    const int rq = hi * 4;

    __syncthreads();   // A-tile dead; smem reusable

    if (isInit) {
        #pragma unroll
        for (int n = 0; n < 4; ++n) {
            const int c = (colbase & (D - 1)) + n * 16 + r16;
            const float bv = bias[c];
            #pragma unroll
            for (int m = 0; m < 4; ++m)
                #pragma unroll
                for (int q = 0; q < 4; ++q) {
                    const int row = bm + m * 16 + rq + q;
                    if (row < N_NODES)
                        Xinit[(size_t)row * D + c] = acc[m][n][q] + bv;
                }
        }
    } else {
        __half* sh = (__half*)smem;
        #pragma unroll
        for (int n = 0; n < 4; ++n) {
            const int lc = (colbase - D) + n * 16 + r16;   // 0..127
            const float bv = bias[(colbase & (D - 1)) + n * 16 + r16];
            #pragma unroll
            for (int m = 0; m < 4; ++m)
                #pragma unroll
                for (int q = 0; q < 4; ++q)
                    sh[(m * 16 + rq + q) * 128 + lc] =
                        __float2half(acc[m][n][q] + bv);
        }
    }
    __syncthreads();
    // coalesced Xf16 store + fused score (4 threads per row)
    {
        const int r   = tid >> 2;
        const int row = bm + r;
        const int q4  = tid & 3;
        if (row < N_NODES) {
            const char* src = smem + r * 256 + q4 * 64;
            __half* dst = Xf16 + (size_t)row * D + q4 * 32;
            float part = 0.f;
            #pragma unroll
            for (int j = 0; j < 4; ++j) {
                half8 h = *(const half8*)(src + j * 16);
                *(half8*)(dst + j * 8) = h;
                float4 a0 = *(const float4*)(aw + q4 * 32 + j * 8);
                float4 a1 = *(const float4*)(aw + q4 * 32 + j * 8 + 4);
                part += (float)h[0]*a0.x + (float)h[1]*a0.y
                      + (float)h[2]*a0.z + (float)h[3]*a0.w
                      + (float)h[4]*a1.x + (float)h[5]*a1.y
                      + (float)h[6]*a1.z + (float)h[7]*a1.w;
            }
            part += __shfl_xor(part, 1, 64);
            part += __shfl_xor(part, 2, 64);
            if (q4 == 0) {
                float l = (part > 0.f) ? part : NEG_SLOPE * part;
                wexp[row] = expf(l);
            }
        }
    }
}

// ---------------------------------------------------------------------------
// K3: MERGED histogram+rank kernel. Blocks [0,NBLK_E) do edge chunks
// (single pass, all 20000 bins); blocks [NBLK_E, NBLK_E+NBLK_N*NPASS_N)
// do node (chunk, pass) pairs. Both paths: 40 KB packed-ushort LDS bins,
// rank = halfword of LDS atomicAdd return.
// ---------------------------------------------------------------------------
__global__ __launch_bounds__(256) void k_part_all(
    const int* __restrict__ E, const int* __restrict__ V,
    unsigned short* __restrict__ part_e, unsigned short* __restrict__ part_n,
    unsigned short* __restrict__ re, unsigned short* __restrict__ rn)
{
    __shared__ int h[H32_E];   // 10000 ints = 40 KB (H32_E == H32_N)
    const int blk = blockIdx.x;
    for (int t = threadIdx.x; t < H32_E; t += 256) h[t] = 0;
    __syncthreads();

    if (blk < NBLK_E) {
        const int b = blk;
        const int i0 = b * CHUNK_E;
        const int4* E4 = (const int4*)(E + i0);
        for (int i = threadIdx.x; i < CHUNK_E / 4; i += 256) {
            int4 q = E4[i];
            int ev[4] = {q.x, q.y, q.z, q.w};
            #pragma unroll
            for (int t = 0; t < 4; ++t) {
                int e = ev[t];
                unsigned sh = (e & 1) << 4;
                int old = atomicAdd(&h[e >> 1], 1 << sh);
                re[i0 + i * 4 + t] = (unsigned short)((unsigned)old >> sh);
            }
        }
        __syncthreads();
        int* dst = (int*)(part_e + (size_t)b * N_EDGES);
        for (int t = threadIdx.x; t < H32_E; t += 256) dst[t] = h[t];
    } else {
        const int idx = blk - NBLK_E;        // 0..319
        const int b   = idx & 63;            // node chunk
        const int c0  = (idx >> 6) * BINS_N; // pass * 20000
        const int i0  = b * CHUNK_N;
        const int4* V4 = (const int4*)(V + i0);
        for (int i = threadIdx.x; i < CHUNK_N / 4; i += 256) {
            int4 q = V4[i];
            int vv[4] = {q.x, q.y, q.z, q.w};
            #pragma unroll
            for (int t = 0; t < 4; ++t) {
                int c = vv[t] - c0;
                if ((unsigned)c < (unsigned)BINS_N) {
                    unsigned sh = (c & 1) << 4;
                    int old = atomicAdd(&h[c >> 1], 1 << sh);
                    rn[i0 + i * 4 + t] = (unsigned short)((unsigned)old >> sh);
                }
            }
        }
        __syncthreads();
        int* dst = (int*)(part_n + (size_t)b * N_NODES + c0);
        for (int t = threadIdx.x; t < H32_N; t += 256) dst[t] = h[t];
    }
}

// ---------------------------------------------------------------------------
// K5a: within-GROUP exclusive scan over chunks (level 1 of 2).
// ---------------------------------------------------------------------------
__global__ __launch_bounds__(256) void k_tot_grp(
    unsigned short* __restrict__ part, int* __restrict__ gsum,
    int nbins, int cpg)
{
    int bin = blockIdx.x * 256 + threadIdx.x;
    if (bin >= nbins) return;
    const int g = blockIdx.y;
    int run = 0;
    #pragma unroll 10
    for (int b = g * cpg; b < (g + 1) * cpg; ++b) {
        size_t idx = (size_t)b * nbins + bin;
        int v = part[idx];
        part[idx] = (unsigned short)run;
        run += v;
    }
    gsum[(size_t)g * nbins + bin] = run;
}

// ---------------------------------------------------------------------------
// K5b: exclusive scan over the NGRP group sums (level 2); emits tot.
// ---------------------------------------------------------------------------
__global__ __launch_bounds__(256) void k_tot_fin(
    int* __restrict__ gsum, int* __restrict__ tot, int nbins)
{
    int bin = blockIdx.x * 256 + threadIdx.x;
    if (bin >= nbins) return;
    int run = 0;
    #pragma unroll
    for (int g = 0; g < NGRP; ++g) {
        size_t idx = (size_t)g * nbins + bin;
        int v = gsum[idx];
        gsum[idx] = run;
        run += v;
    }
    tot[bin] = run;
}

// ---------------------------------------------------------------------------
// Multi-block scan, phase 1: per-block sums. 256 thr x 16 elems (int4).
// ---------------------------------------------------------------------------
__global__ __launch_bounds__(256) void k_scan_bsum(
    const int* __restrict__ cnt, int* __restrict__ bsum, int n)
{
    __shared__ int red[256];
    const int base = blockIdx.x * SC_PER_BLOCK + threadIdx.x * SCC;
    int s = 0;
    if (base + SCC <= n) {
        const int4* p4 = (const int4*)(cnt + base);
        #pragma unroll
        for (int j = 0; j < SCC / 4; ++j) {
            int4 v = p4[j];
            s += v.x + v.y + v.z + v.w;
        }
    } else {
        for (int i = base; i < n; ++i) s += cnt[i];
    }
    red[threadIdx.x] = s;
    __syncthreads();
    for (int d = 128; d > 0; d >>= 1) {
        if (threadIdx.x < d) red[threadIdx.x] += red[threadIdx.x + d];
        __syncthreads();
    }
    if (threadIdx.x == 0) bsum[blockIdx.x] = red[0];
}

// ---------------------------------------------------------------------------
// Phase 2: exclusive block bases; writes total into off[n].  nb <= 1024.
// ---------------------------------------------------------------------------
__global__ __launch_bounds__(1024) void k_scan_bbase(
    int* __restrict__ bsum, int nb, int* __restrict__ off, int n)
{
    __shared__ int sums[1024];
    const int tid = threadIdx.x;
    sums[tid] = (tid < nb) ? bsum[tid] : 0;
    __syncthreads();
    for (int d = 1; d < 1024; d <<= 1) {
        int mine = sums[tid];
        int other = (tid >= d) ? sums[tid - d] : 0;
        __syncthreads();
        sums[tid] = mine + other;
        __syncthreads();
    }
    if (tid < nb) bsum[tid] = (tid > 0) ? sums[tid - 1] : 0;
    if (tid == 0) off[n] = sums[1023];
}

// ---------------------------------------------------------------------------
// Phase 3: per-block exclusive scan + block base -> off[i].
// ---------------------------------------------------------------------------
__global__ __launch_bounds__(256) void k_scan_out(
    const int* __restrict__ cnt, const int* __restrict__ bsum,
    int* __restrict__ off, int n)
{
    __shared__ int tsum[256];
    const int base = blockIdx.x * SC_PER_BLOCK + threadIdx.x * SCC;
    int vals[SCC];
    int s = 0;
    if (base + SCC <= n) {
        const int4* p4 = (const int4*)(cnt + base);
        #pragma unroll
        for (int j = 0; j < SCC / 4; ++j) {
            int4 v = p4[j];
            vals[4 * j + 0] = v.x; vals[4 * j + 1] = v.y;
            vals[4 * j + 2] = v.z; vals[4 * j + 3] = v.w;
            s += v.x + v.y + v.z + v.w;
        }
    } else {
        #pragma unroll
        for (int j = 0; j < SCC; ++j) {
            int i = base + j;
            vals[j] = (i < n) ? cnt[i] : 0;
            s += vals[j];
        }
    }
    tsum[threadIdx.x] = s;
    __syncthreads();
    for (int d = 1; d < 256; d <<= 1) {
        int mine = tsum[threadIdx.x];
        int other = (threadIdx.x >= d) ? tsum[threadIdx.x - d] : 0;
        __syncthreads();
        tsum[threadIdx.x] = mine + other;
        __syncthreads();
    }
    int run = bsum[blockIdx.x] + ((threadIdx.x > 0) ? tsum[threadIdx.x - 1] : 0);
    #pragma unroll
    for (int j = 0; j < SCC; ++j) {
        int i = base + j;
        if (i < n) { off[i] = run; run += vals[j]; }
    }
}

// ---------------------------------------------------------------------------
// K6: FUSED flat scatter, XCD-CHUNKED. Round-8 counters showed WRITE =
// 1.6M x 64B (every store = full-line RFO+WB, multiplied by the ~8 XCDs
// touching each line). Output layout is group-major per bin with NGRP=8 ==
// NXCD, so remap blocks bijectively so blocks with bid%8==k (presumed
// XCD k) process the k-th contiguous 1/8 of incidences = group k. Then
// each output line is written by ~1 XCD -> one RFO+WB per line.
// Correctness is mapping-independent (pure bijection on i).
// ---------------------------------------------------------------------------
__global__ __launch_bounds__(256) void k_scatter_both(
    const int* __restrict__ V, const int* __restrict__ E,
    const unsigned short* __restrict__ re, const unsigned short* __restrict__ rn,
    const unsigned short* __restrict__ part_e,
    const unsigned short* __restrict__ part_n,
    const int* __restrict__ gsum_e, const int* __restrict__ gsum_n,
    const int* __restrict__ eoff, const int* __restrict__ noff,
    int* __restrict__ epairs, unsigned short* __restrict__ nedges)
{
    const int bid = blockIdx.x;
    const int xcd = bid & 7;
    const int j   = bid >> 3;
    const int vb  = (xcd < SCAT_R) ? xcd * (SCAT_Q + 1) + j
                                   : SCAT_R * (SCAT_Q + 1) + (xcd - SCAT_R) * SCAT_Q + j;
    int i = vb * 256 + (int)threadIdx.x;
    if (i >= NNZ) return;
    int e = E[i], v = V[i];
    int be = i / CHUNK_E;
    int bn = i / CHUNK_N;
    int g  = i / 200000;            // = be/CPG_E = bn/CPG_N
    int pe = eoff[e] + gsum_e[(size_t)g * N_EDGES + e]
                     + part_e[(size_t)be * N_EDGES + e] + re[i];
    int pn = noff[v] + gsum_n[(size_t)g * N_NODES + v]
                     + part_n[(size_t)bn * N_NODES + v] + rn[i];
    epairs[pe] = v;
    nedges[pn] = (unsigned short)e;
}

// ---------------------------------------------------------------------------
// helper: accumulate 8 dims (8 halves packed in a float4) with weight w
// ---------------------------------------------------------------------------
__device__ __forceinline__ void acc8h(float w, float4 raw, float (&a)[8])
{
    const __half2* h = (const __half2*)&raw;
    #pragma unroll
    for (int t = 0; t < 4; ++t) {
        float2 f = __half22float2(h[t]);
        a[2*t]   = fmaf(w, f.x, a[2*t]);
        a[2*t+1] = fmaf(w, f.y, a[2*t+1]);
    }
}

// ---------------------------------------------------------------------------
// K8: per-edge aggregation. ONE WAVE PER EDGE, FOUR 16-LANE SLOTS.
// w gathered from the 400 KB L2-resident wexp table (epairs is v-only).
// ---------------------------------------------------------------------------
__global__ __launch_bounds__(256) void k_edge_agg(
    const int* __restrict__ epairs, const int* __restrict__ eoff,
    const float* __restrict__ wexp,
    const __half* __restrict__ Xf16, const float* __restrict__ S,
    float* __restrict__ emsg)
{
    const int wave = threadIdx.x >> 6, lane = threadIdx.x & 63;
    const int e = blockIdx.x * 4 + wave;
    if (e >= N_EDGES) return;
    const int beg = eoff[e], end = eoff[e + 1];
    const int slot = lane >> 4;          // 0..3
    const int sl = lane & 15;            // dims 8*sl .. 8*sl+7
    float a[8] = {};
    float dsum = 0.f;
    int j = beg;
    #pragma unroll 2
    for (; j + 3 < end; j += 4) {
        int v = epairs[j + slot];
        float w = wexp[v];
        float4 r = *(const float4*)(Xf16 + (size_t)v * D + sl * 8);
        dsum += w;
        acc8h(w, r, a);
    }
    if (j + slot < end) {
        int v = epairs[j + slot];
        float w = wexp[v];
        float4 r = *(const float4*)(Xf16 + (size_t)v * D + sl * 8);
        dsum += w;
        acc8h(w, r, a);
    }
    #pragma unroll
    for (int k = 0; k < 8; ++k) {
        a[k] += __shfl_xor(a[k], 16, 64);
        a[k] += __shfl_xor(a[k], 32, 64);
    }
    dsum += __shfl_xor(dsum, 16, 64);
    dsum += __shfl_xor(dsum, 32, 64);

    float inv = (end > beg) ? 1.f / dsum : 0.f;
    float y[8];
    #pragma unroll
    for (int k = 0; k < 8; ++k) {
        float t = a[k] * inv;
        y[k] = (t > 0.f) ? t : expm1f(t);
    }
    const size_t rb = (size_t)e * (D + STAR);
    if (slot == 0) {
        *(float4*)(emsg + rb + sl * 8)     = make_float4(y[0], y[1], y[2], y[3]);
        *(float4*)(emsg + rb + sl * 8 + 4) = make_float4(y[4], y[5], y[6], y[7]);
    } else if (slot == 1) {
        float4 s4 = *(const float4*)(S + (size_t)e * STAR + sl * 4);
        *(float4*)(emsg + rb + D + sl * 4) = s4;
    }
}

// ---------------------------------------------------------------------------
// K9: edge GEMM on matrix cores: Y = e_msg @ Wt^T + Wt_b -> fp16.
// ---------------------------------------------------------------------------
__global__ __launch_bounds__(256) void k_edge_gemm(
    const float* __restrict__ A, const __half* __restrict__ Wtf16,
    const float* __restrict__ Wtb, __half* __restrict__ Y16)
{
    __shared__ char smem[64 * 384];   // 24 KB A-tile; head reused for repack
    const int KDIM = D + STAR;        // 192
    const int tid  = threadIdx.x;
    const int w    = tid >> 6;
    const int lane = tid & 63;
    const int bm   = blockIdx.x * 64;
    const int colbase = w * 32;       // 0,32,64,96
    const int r16 = lane & 15;
    const int hi  = lane >> 4;
    const int g8  = hi * 8;

    {
        const int r = tid >> 2;
        int srow = bm + r; if (srow >= N_EDGES) srow = N_EDGES - 1;
        const float4* src = (const float4*)(A + (size_t)srow * KDIM + (tid & 3) * 48);
        float4 f[12];
        #pragma unroll
        for (int j = 0; j < 12; ++j) f[j] = src[j];
        const int swz  = (r & 7) << 4;
        const int base = r * 384 + (tid & 3) * 96;
        #pragma unroll
        for (int j = 0; j < 6; ++j)
            *(half8*)(smem + ((base + j * 16) ^ swz)) = cvt8(f[2*j], f[2*j+1]);
    }

    half8 bf[6][2];
    #pragma unroll
    for (int ks = 0; ks < 6; ++ks)
        #pragma unroll
        for (int n = 0; n < 2; ++n)
            bf[ks][n] = *(const half8*)(Wtf16 + (size_t)(colbase + n*16 + r16) * KDIM
                                        + ks * 32 + g8);

    __syncthreads();

    floatx4 acc[4][2] = {};
    #pragma unroll
    for (int ks = 0; ks < 6; ++ks) {
        half8 a[4];
        #pragma unroll
        for (int m = 0; m < 4; ++m) {
            const int R = m * 16 + r16;
            a[m] = *(const half8*)(smem + ((R*384 + ks*64 + hi*16) ^ ((R&7)<<4)));
        }
        #pragma unroll
        for (int m = 0; m < 4; ++m)
            #pragma unroll
            for (int n = 0; n < 2; ++n)
                acc[m][n] = __builtin_amdgcn_mfma_f32_16x16x32_f16(
                    a[m], bf[ks][n], acc[m][n], 0, 0, 0);
    }

    const int rq = hi * 4;
    __syncthreads();   // A-tile dead

    {
        __half* sh = (__half*)smem;
        #pragma unroll
        for (int n = 0; n < 2; ++n) {
            const int c = colbase + n * 16 + r16;     // 0..127
            const float bv = Wtb[c];
            #pragma unroll
            for (int m = 0; m < 4; ++m)
                #pragma unroll
                for (int q = 0; q < 4; ++q)
                    sh[(m * 16 + rq + q) * 128 + c] =
                        __float2half(acc[m][n][q] + bv);
        }
    }
    __syncthreads();
    {
        const int r   = tid >> 2;
        const int row = bm + r;
        if (row < N_EDGES) {
            const char* src = smem + r * 256 + (tid & 3) * 64;
            __half* dst = Y16 + (size_t)row * D + (tid & 3) * 32;
            #pragma unroll
            for (int j = 0; j < 4; ++j)
                *(half8*)(dst + j * 8) = *(const half8*)(src + j * 16);
        }
    }
}

// ---------------------------------------------------------------------------
// K10: per-node aggregation. ONE WAVE PER NODE, FOUR 16-LANE SLOTS.
// out[v] = elu(mean_j Y[e_j]) + out[v]   (out holds X_init).
// ---------------------------------------------------------------------------
__global__ __launch_bounds__(256) void k_node_agg(
    const unsigned short* __restrict__ nedges, const int* __restrict__ noff,
    const __half* __restrict__ Y16, float* __restrict__ out)
{
    const int wave = threadIdx.x >> 6, lane = threadIdx.x & 63;
    const int v = blockIdx.x * 4 + wave;
    if (v >= N_NODES) return;
    const int beg = noff[v], end = noff[v + 1];
    const int slot = lane >> 4;
    const int sl = lane & 15;
    float a[8] = {};
    int j = beg;
    #pragma unroll 2
    for (; j + 3 < end; j += 4) {
        int e0 = nedges[j + slot];
        float4 r = *(const float4*)(Y16 + (size_t)e0 * D + sl * 8);
        acc8h(1.f, r, a);
    }
    if (j + slot < end) {
        int e0 = nedges[j + slot];
        float4 r = *(const float4*)(Y16 + (size_t)e0 * D + sl * 8);
        acc8h(1.f, r, a);
    }
    #pragma unroll
    for (int k = 0; k < 8; ++k) {
        a[k] += __shfl_xor(a[k], 16, 64);
        a[k] += __shfl_xor(a[k], 32, 64);
    }

    if (slot == 0) {
        int cnt = end - beg;
        float invc = 1.f / (float)max(cnt, 1);
        float x[8];
        #pragma unroll
        for (int k = 0; k < 8; ++k) {
            float t = a[k] * invc;
            x[k] = (t > 0.f) ? t : expm1f(t);
        }
        float4* o0 = (float4*)(out + (size_t)v * D + sl * 8);
        float4* o1 = (float4*)(out + (size_t)v * D + sl * 8 + 4);
        float4 c0 = *o0, c1 = *o1;
        *o0 = make_float4(c0.x + x[0], c0.y + x[1], c0.z + x[2], c0.w + x[3]);
        *o1 = make_float4(c1.x + x[4], c1.y + x[5], c1.z + x[6], c1.w + x[7]);
    }
}

// ---------------------------------------------------------------------------
extern "C" void kernel_launch(void* const* d_in, const int* in_sizes, int n_in,
                              void* d_out, int out_size, void* d_ws, size_t ws_size,
                              hipStream_t stream)
{
    const float* X    = (const float*)d_in[0];
    const int*   V    = (const int*)  d_in[1];
    const int*   E    = (const int*)  d_in[2];
    const float* S    = (const float*)d_in[3];
    const float* Wx_w = (const float*)d_in[4];
    const float* Wx_b = (const float*)d_in[5];
    const float* Wv_w = (const float*)d_in[6];
    const float* Wv_b = (const float*)d_in[7];
    const float* a_w  = (const float*)d_in[8];
    const float* Wt_w = (const float*)d_in[9];
    const float* Wt_b = (const float*)d_in[10];
    float* out = (float*)d_out;

    char* p = (char*)d_ws;
    auto take = [&](size_t bytes) -> char* {
        char* r = p;
        p += (bytes + 255) & ~(size_t)255;
        return r;
    };

    __half* Xf16  = (__half*)take((size_t)N_NODES * D * 2);
    float*  wexp  = (float*) take((size_t)N_NODES * 4);
    unsigned short* part_e = (unsigned short*)take((size_t)NBLK_E * N_EDGES * 2);
    unsigned short* part_n = (unsigned short*)take((size_t)NBLK_N * N_NODES * 2);
    int*    gsum_e = (int*)  take((size_t)NGRP * N_EDGES * 4);
    int*    gsum_n = (int*)  take((size_t)NGRP * N_NODES * 4);
    int*    tot_e = (int*)   take((size_t)N_EDGES * 4);
    int*    tot_n = (int*)   take((size_t)N_NODES * 4);
    int*    eoff  = (int*)   take((size_t)(N_EDGES + 1) * 4);
    int*    noff  = (int*)   take((size_t)(N_NODES + 1) * 4);
    int*    bsum_e = (int*)  take((size_t)SC_NBLK(N_EDGES) * 4);
    int*    bsum_n = (int*)  take((size_t)SC_NBLK(N_NODES) * 4);
    unsigned short* re = (unsigned short*)take((size_t)NNZ * 2);
    unsigned short* rn = (unsigned short*)take((size_t)NNZ * 2);
    int*    epairs = (int*)  take((size_t)NNZ * 4);
    unsigned short* nedges = (unsigned short*)take((size_t)NNZ * 2);
    float*  emsg  = (float*) take((size_t)N_EDGES * (D + STAR) * 4);
    __half* Y16   = (__half*)take((size_t)N_EDGES * D * 2);
    __half* Wf16  = (__half*)take((size_t)256 * D * 2);          // [Wx;Wv] fp16
    __half* Wtf16 = (__half*)take((size_t)D * (D + STAR) * 2);   // Wt fp16

    k_cvt_w<<<56, 256, 0, stream>>>(Wx_w, Wv_w, Wt_w, Wf16, Wtf16);

    k_node_gemm<<<(N_NODES + 63) / 64, 256, 0, stream>>>(
        X, Wf16, Wx_b, Wv_b, a_w, out, Xf16, wexp);

    k_part_all<<<NBLK_E + NBLK_N * NPASS_N, 256, 0, stream>>>(
        E, V, part_e, part_n, re, rn);

    // two-level chunk scans (8 groups each)
    k_tot_grp<<<dim3((N_EDGES + 255) / 256, NGRP), 256, 0, stream>>>(
        part_e, gsum_e, N_EDGES, CPG_E);
    k_tot_grp<<<dim3((N_NODES + 255) / 256, NGRP), 256, 0, stream>>>(
        part_n, gsum_n, N_NODES, CPG_N);
    k_tot_fin<<<(N_EDGES + 255) / 256, 256, 0, stream>>>(gsum_e, tot_e, N_EDGES);
    k_tot_fin<<<(N_NODES + 255) / 256, 256, 0, stream>>>(gsum_n, tot_n, N_NODES);

    // edge scan (n = 20000, 5 blocks)
    k_scan_bsum<<<SC_NBLK(N_EDGES), 256, 0, stream>>>(tot_e, bsum_e, N_EDGES);
    k_scan_bbase<<<1, 1024, 0, stream>>>(bsum_e, SC_NBLK(N_EDGES), eoff, N_EDGES);
    k_scan_out<<<SC_NBLK(N_EDGES), 256, 0, stream>>>(tot_e, bsum_e, eoff, N_EDGES);

    // node scan (n = 100000, 25 blocks)
    k_scan_bsum<<<SC_NBLK(N_NODES), 256, 0, stream>>>(tot_n, bsum_n, N_NODES);
    k_scan_bbase<<<1, 1024, 0, stream>>>(bsum_n, SC_NBLK(N_NODES), noff, N_NODES);
    k_scan_out<<<SC_NBLK(N_NODES), 256, 0, stream>>>(tot_n, bsum_n, noff, N_NODES);

    k_scatter_both<<<SCAT_NWG, 256, 0, stream>>>(
        V, E, re, rn, part_e, part_n, gsum_e, gsum_n,
        eoff, noff, epairs, nedges);

    k_edge_agg<<<(N_EDGES + 3) / 4, 256, 0, stream>>>(
        epairs, eoff, wexp, Xf16, S, emsg);

    k_edge_gemm<<<(N_EDGES + 63) / 64, 256, 0, stream>>>(emsg, Wtf16, Wt_b, Y16);

    k_node_agg<<<(N_NODES + 3) / 4, 256, 0, stream>>>(nedges, noff, Y16, out);
}